// Round 8
// baseline (533.621 us; speedup 1.0000x reference)
//
#include <hip/hip_runtime.h>
#include <hip/hip_bf16.h>
#include <hip/hip_fp8.h>
#include <math.h>

#define N_NODES 100000
#define DIM 64
#define NUM_LAYER 3
#define BATCH 4096
#define REG_WEIGHT 1e-4f
#define SCAN_BLOCKS ((N_NODES + 255) / 256)   // 391
#define NBUCKET 391                            // dst >> 8 buckets (256 nodes each)
#define H_SCALE 64.0f
#define H_INV_SCALE (1.0f / 64.0f)

// Scratch as device globals (ws_size unknown; this pattern passed R2/R3/R5/R6/R7).
__device__ unsigned char g_hf8[2][(size_t)N_NODES * DIM]; // fp8 ping-pong h (scaled)
__device__ float g_sums[(size_t)3 * BATCH * DIM];  // sampled-row accumulators (f32)
__device__ int   g_cnt[N_NODES];                   // in-degree counts
__device__ int   g_fill[N_NODES];                  // CSR fill cursors
__device__ int   g_row_ptr[N_NODES + 1];           // CSR row offsets (by dst)
__device__ int   g_partials[SCAN_BLOCKS];          // scan partials
__device__ float g_dinv[N_NODES];                  // deg^-0.5
__device__ int   g_subcnt[NBUCKET * 8];            // per (bucket, blockIdx&7) edge counts
__device__ int   g_subcur[NBUCKET * 8];            // append cursors
__device__ int2  g_stage[1280000];                 // staged (src, dst), bucket-grouped
__device__ int2  g_csr[1280000];                   // final packed (src, w-bits) per edge
__device__ float g_part_sp[BATCH];                 // per-wave softplus partials
__device__ float g_part_rg[BATCH];                 // per-wave reg partials

__device__ inline float fp8_to_f32(unsigned char v) {
    __hip_fp8_e4m3 t; t.__x = (__hip_fp8_storage_t)v; return (float)t;
}
__device__ inline unsigned char f32_to_fp8(float f) {
    __hip_fp8_e4m3 t(f); return (unsigned char)t.__x;
}

// ---- zero the small per-call state ----
__global__ void zero_small() {
    size_t i = (size_t)blockIdx.x * blockDim.x + threadIdx.x;
    size_t stride = (size_t)gridDim.x * blockDim.x;
    for (size_t k = i; k < (size_t)3 * BATCH * DIM; k += stride) g_sums[k] = 0.0f;
    for (size_t k = i; k < N_NODES; k += stride) { g_cnt[k] = 0; g_fill[k] = 0; }
    for (size_t k = i; k < NBUCKET * 8; k += stride) g_subcnt[k] = 0;
}

// ---- fused: degree count + (bucket,sub) count. blockIdx&7 must match append_pass ----
__global__ void count_pass(const int* __restrict__ dst, int E) {
    int e = blockIdx.x * blockDim.x + threadIdx.x;
    if (e >= E) return;
    int d = dst[e];
    atomicAdd(&g_cnt[d], 1);
    atomicAdd(&g_subcnt[((d >> 8) << 3) + (blockIdx.x & 7)], 1);
}

// ---- dinv from counts ----
__global__ void make_dinv() {
    int v = blockIdx.x * blockDim.x + threadIdx.x;
    if (v < N_NODES) {
        int c = g_cnt[v];
        g_dinv[v] = (c > 0) ? rsqrtf((float)c) : 0.0f;
    }
}

// ---- exclusive scan of g_cnt -> g_row_ptr, 3 phases ----
__global__ void scan_blocks() {
    __shared__ int sm[256];
    int i = blockIdx.x * 256 + threadIdx.x;
    int v = (i < N_NODES) ? g_cnt[i] : 0;
    sm[threadIdx.x] = v;
    __syncthreads();
    for (int off = 1; off < 256; off <<= 1) {
        int t = (threadIdx.x >= off) ? sm[threadIdx.x - off] : 0;
        __syncthreads();
        sm[threadIdx.x] += t;
        __syncthreads();
    }
    if (i < N_NODES) g_row_ptr[i] = sm[threadIdx.x] - v;  // exclusive
    if (threadIdx.x == 255) g_partials[blockIdx.x] = sm[255];
}

__global__ void scan_partials_fast(int E) {
    __shared__ int sm[512];
    int t = threadIdx.x;
    int v = (t < SCAN_BLOCKS) ? g_partials[t] : 0;
    sm[t] = v;
    __syncthreads();
    for (int off = 1; off < 512; off <<= 1) {
        int x = (t >= off) ? sm[t - off] : 0;
        __syncthreads();
        sm[t] += x;
        __syncthreads();
    }
    if (t < SCAN_BLOCKS) g_partials[t] = sm[t] - v;  // exclusive
    if (t == 0) g_row_ptr[N_NODES] = E;
}

__global__ void scan_add() {
    int i = blockIdx.x * 256 + threadIdx.x;
    if (i < N_NODES) g_row_ptr[i] += g_partials[blockIdx.x];
}

// ---- per-(bucket,sub) append cursors: row_ptr[bucket base] + prefix of sub counts ----
__global__ void sub_offsets() {
    int i = blockIdx.x * blockDim.x + threadIdx.x;
    if (i >= NBUCKET * 8) return;
    int b = i >> 3, c = i & 7;
    int off = g_row_ptr[b << 8];
    for (int j = 0; j < c; ++j) off += g_subcnt[(b << 3) + j];
    g_subcur[i] = off;
}

// ---- pass A: append (src,dst) sequentially into (bucket,sub) staging regions ----
__global__ void append_pass(const int* __restrict__ src, const int* __restrict__ dst, int E) {
    int e = blockIdx.x * blockDim.x + threadIdx.x;
    if (e >= E) return;
    int s = src[e], d = dst[e];
    int pos = atomicAdd(&g_subcur[((d >> 8) << 3) + (blockIdx.x & 7)], 1);
    g_stage[pos] = make_int2(s, d);
}

// ---- pass B: one block per bucket; scatter staged edges into the bucket's 26 KB CSR window ----
__global__ void bucket_sort() {
    int b = blockIdx.x;
    int beg  = g_row_ptr[b << 8];
    int endn = min(N_NODES, (b + 1) << 8);
    int end  = g_row_ptr[endn];
    for (int k = beg + threadIdx.x; k < end; k += blockDim.x) {
        int2 sd = g_stage[k];
        int s = sd.x, d = sd.y;
        int pos = g_row_ptr[d] + atomicAdd(&g_fill[d], 1);
        float w = g_dinv[s] * g_dinv[d];
        g_csr[pos] = make_int2(s, __float_as_int(w));
    }
}

// ---- convert emb (f32) to scaled fp8 ----
__global__ void emb_to_fp8(const float* __restrict__ emb, unsigned char* __restrict__ hf) {
    size_t i = (size_t)blockIdx.x * blockDim.x + threadIdx.x;
    size_t stride = (size_t)gridDim.x * blockDim.x;
    for (size_t k = i; k < (size_t)N_NODES * DIM; k += stride)
        hf[k] = f32_to_fp8(emb[k] * H_SCALE);
}

// ---- pull one layer (fp8 scaled domain, f32 acc): wave per dst, 4-way unroll ----
__global__ void pull_layer_fp8(const unsigned char* __restrict__ h,
                               unsigned char* __restrict__ hn) {
    int wid  = (blockIdx.x * blockDim.x + threadIdx.x) >> 6;
    int lane = threadIdx.x & 63;
    if (wid >= N_NODES) return;
    int beg = g_row_ptr[wid], end = g_row_ptr[wid + 1];
    float acc = 0.0f;
    for (int base = beg; base < end; base += 64) {
        int k = base + lane;
        int s = 0; float w = 0.0f;
        if (k < end) { int2 ew = g_csr[k]; s = ew.x; w = __int_as_float(ew.y); }
        int cnt = min(64, end - base);
        int j = 0;
        for (; j + 4 <= cnt; j += 4) {   // 4 independent gathers in flight
            int   s0 = __shfl(s, j),     s1 = __shfl(s, j + 1);
            int   s2 = __shfl(s, j + 2), s3 = __shfl(s, j + 3);
            float w0 = __shfl(w, j),     w1 = __shfl(w, j + 1);
            float w2 = __shfl(w, j + 2), w3 = __shfl(w, j + 3);
            float h0 = fp8_to_f32(h[(size_t)s0 * DIM + lane]);
            float h1 = fp8_to_f32(h[(size_t)s1 * DIM + lane]);
            float h2 = fp8_to_f32(h[(size_t)s2 * DIM + lane]);
            float h3 = fp8_to_f32(h[(size_t)s3 * DIM + lane]);
            acc = fmaf(w0, h0, acc); acc = fmaf(w1, h1, acc);
            acc = fmaf(w2, h2, acc); acc = fmaf(w3, h3, acc);
        }
        for (; j < cnt; ++j) {
            int   ss = __shfl(s, j);
            float ww = __shfl(w, j);
            acc = fmaf(ww, fp8_to_f32(h[(size_t)ss * DIM + lane]), acc);
        }
    }
    hn[(size_t)wid * DIM + lane] = f32_to_fp8(acc);
}

// ---- final layer: pull ONLY the sampled rows, add into g_sums (unscale here) ----
__global__ void pull_sampled(const unsigned char* __restrict__ h,
                             const int* __restrict__ users, const int* __restrict__ pos,
                             const int* __restrict__ neg) {
    int wid  = (blockIdx.x * blockDim.x + threadIdx.x) >> 6;
    int lane = threadIdx.x & 63;
    if (wid >= 3 * BATCH) return;
    int which = wid / BATCH;
    int i     = wid - which * BATCH;
    const int* idx = (which == 0) ? users : ((which == 1) ? pos : neg);
    int node = idx[i];
    int beg = g_row_ptr[node], end = g_row_ptr[node + 1];
    float acc = 0.0f;
    for (int base = beg; base < end; base += 64) {
        int k = base + lane;
        int s = 0; float w = 0.0f;
        if (k < end) { int2 ew = g_csr[k]; s = ew.x; w = __int_as_float(ew.y); }
        int cnt = min(64, end - base);
        int j = 0;
        for (; j + 4 <= cnt; j += 4) {
            int   s0 = __shfl(s, j),     s1 = __shfl(s, j + 1);
            int   s2 = __shfl(s, j + 2), s3 = __shfl(s, j + 3);
            float w0 = __shfl(w, j),     w1 = __shfl(w, j + 1);
            float w2 = __shfl(w, j + 2), w3 = __shfl(w, j + 3);
            float h0 = fp8_to_f32(h[(size_t)s0 * DIM + lane]);
            float h1 = fp8_to_f32(h[(size_t)s1 * DIM + lane]);
            float h2 = fp8_to_f32(h[(size_t)s2 * DIM + lane]);
            float h3 = fp8_to_f32(h[(size_t)s3 * DIM + lane]);
            acc = fmaf(w0, h0, acc); acc = fmaf(w1, h1, acc);
            acc = fmaf(w2, h2, acc); acc = fmaf(w3, h3, acc);
        }
        for (; j < cnt; ++j) {
            int   ss = __shfl(s, j);
            float ww = __shfl(w, j);
            acc = fmaf(ww, fp8_to_f32(h[(size_t)ss * DIM + lane]), acc);
        }
    }
    g_sums[(size_t)wid * DIM + lane] += acc * H_INV_SCALE;  // wid owns row; no atomics
}

// ---- gather sampled rows (f32 source: layer 0 = emb) ----
__global__ void gather_acc_f32(const float* __restrict__ h,
                               const int* __restrict__ users, const int* __restrict__ pos,
                               const int* __restrict__ neg) {
    int wid  = (blockIdx.x * blockDim.x + threadIdx.x) >> 6;
    int lane = threadIdx.x & 63;
    if (wid >= 3 * BATCH) return;
    int which = wid / BATCH;
    int i     = wid - which * BATCH;
    const int* idx = (which == 0) ? users : ((which == 1) ? pos : neg);
    int node = idx[i];
    g_sums[(size_t)wid * DIM + lane] += h[(size_t)node * DIM + lane];
}

// ---- gather sampled rows (fp8 scaled source: layers 1,2) ----
__global__ void gather_acc_fp8(const unsigned char* __restrict__ h,
                               const int* __restrict__ users, const int* __restrict__ pos,
                               const int* __restrict__ neg) {
    int wid  = (blockIdx.x * blockDim.x + threadIdx.x) >> 6;
    int lane = threadIdx.x & 63;
    if (wid >= 3 * BATCH) return;
    int which = wid / BATCH;
    int i     = wid - which * BATCH;
    const int* idx = (which == 0) ? users : ((which == 1) ? pos : neg);
    int node = idx[i];
    g_sums[(size_t)wid * DIM + lane] += fp8_to_f32(h[(size_t)node * DIM + lane]) * H_INV_SCALE;
}

// ---- per-sample scores + reg partials, wave-64 reduce, partials to arrays (NO atomics) ----
__global__ void score_reduce(const float* __restrict__ emb,
                             const int* __restrict__ users, const int* __restrict__ pos,
                             const int* __restrict__ neg) {
    int wid  = (blockIdx.x * blockDim.x + threadIdx.x) >> 6;
    int lane = threadIdx.x & 63;
    if (wid >= BATCH) return;
    float u = 0.25f * g_sums[(size_t)wid * DIM + lane];
    float p = 0.25f * g_sums[(size_t)(BATCH + wid) * DIM + lane];
    float n = 0.25f * g_sums[(size_t)(2 * BATCH + wid) * DIM + lane];
    float ps = u * p;
    float ns = u * n;
    float u0 = emb[(size_t)users[wid] * DIM + lane];
    float p0 = emb[(size_t)pos[wid]   * DIM + lane];
    float n0 = emb[(size_t)neg[wid]   * DIM + lane];
    float rg = u0 * u0 + p0 * p0 + n0 * n0;
    #pragma unroll
    for (int off = 32; off > 0; off >>= 1) {
        ps += __shfl_down(ps, off);
        ns += __shfl_down(ns, off);
        rg += __shfl_down(rg, off);
    }
    if (lane == 0) {
        float x  = ns - ps;
        float sp = fmaxf(x, 0.0f) + log1pf(expf(-fabsf(x)));  // stable softplus
        g_part_sp[wid] = sp;
        g_part_rg[wid] = rg;
    }
}

// ---- single-block final reduction over the 4096 per-wave partials ----
__global__ void final_reduce(float* __restrict__ out) {
    __shared__ float s_sp[256], s_rg[256];
    int t = threadIdx.x;
    float sp = 0.0f, rg = 0.0f;
    for (int i = t; i < BATCH; i += 256) { sp += g_part_sp[i]; rg += g_part_rg[i]; }
    s_sp[t] = sp; s_rg[t] = rg;
    __syncthreads();
    for (int off = 128; off > 0; off >>= 1) {
        if (t < off) { s_sp[t] += s_sp[t + off]; s_rg[t] += s_rg[t + off]; }
        __syncthreads();
    }
    if (t == 0) {
        float loss_emb = s_sp[0] / (float)BATCH;
        float reg      = 0.5f * s_rg[0] / (float)BATCH * REG_WEIGHT;
        out[0] = loss_emb + reg;
        out[1] = loss_emb;
        out[2] = reg;
    }
}

extern "C" void kernel_launch(void* const* d_in, const int* in_sizes, int n_in,
                              void* d_out, int out_size, void* d_ws, size_t ws_size,
                              hipStream_t stream) {
    const float* emb   = (const float*)d_in[0];
    const int*   src   = (const int*)d_in[1];
    const int*   dst   = (const int*)d_in[2];
    const int*   users = (const int*)d_in[3];
    const int*   pos   = (const int*)d_in[4];
    const int*   neg   = (const int*)d_in[5];
    const int E = in_sizes[1];
    float* out = (float*)d_out;

    unsigned char* hf_a;  hipGetSymbolAddress((void**)&hf_a, HIP_SYMBOL(g_hf8));
    unsigned char* hf_b = hf_a + (size_t)N_NODES * DIM;

    const int EBLOCKS = (E + 255) / 256;   // identical geometry for count/append passes

    zero_small<<<1024, 256, 0, stream>>>();
    count_pass<<<EBLOCKS, 256, 0, stream>>>(dst, E);
    make_dinv<<<(N_NODES + 255) / 256, 256, 0, stream>>>();

    scan_blocks<<<SCAN_BLOCKS, 256, 0, stream>>>();
    scan_partials_fast<<<1, 512, 0, stream>>>(E);
    scan_add<<<SCAN_BLOCKS, 256, 0, stream>>>();
    sub_offsets<<<(NBUCKET * 8 + 255) / 256, 256, 0, stream>>>();
    append_pass<<<EBLOCKS, 256, 0, stream>>>(src, dst, E);
    bucket_sort<<<NBUCKET, 256, 0, stream>>>();

    emb_to_fp8<<<2048, 256, 0, stream>>>(emb, hf_a);

    // layer 0 contribution (emb itself, f32)
    gather_acc_f32<<<(3 * BATCH * 64 + 255) / 256, 256, 0, stream>>>(emb, users, pos, neg);

    // layer 1: full pull (needed as input to layer 2)
    pull_layer_fp8<<<(N_NODES * 64 + 255) / 256, 256, 0, stream>>>(hf_a, hf_b);
    gather_acc_fp8<<<(3 * BATCH * 64 + 255) / 256, 256, 0, stream>>>(hf_b, users, pos, neg);

    // layer 2: full pull (needed as input to layer 3's sampled pull)
    pull_layer_fp8<<<(N_NODES * 64 + 255) / 256, 256, 0, stream>>>(hf_b, hf_a);
    gather_acc_fp8<<<(3 * BATCH * 64 + 255) / 256, 256, 0, stream>>>(hf_a, users, pos, neg);

    // layer 3: only the 3*BATCH sampled rows are ever read — pull just those
    pull_sampled<<<(3 * BATCH * 64 + 255) / 256, 256, 0, stream>>>(hf_a, users, pos, neg);

    score_reduce<<<(BATCH * 64 + 255) / 256, 256, 0, stream>>>(emb, users, pos, neg);
    final_reduce<<<1, 256, 0, stream>>>(out);
}

// Round 9
// 339.129 us; speedup vs baseline: 1.5735x; 1.5735x over previous
//
#include <hip/hip_runtime.h>
#include <hip/hip_fp8.h>
#include <math.h>

#define N_NODES 100000
#define DIM 64
#define NUM_LAYER 3
#define BATCH 4096
#define REG_WEIGHT 1e-4f
#define SCAN_BLOCKS ((N_NODES + 255) / 256)   // 391
#define H_SCALE 64.0f
#define H_INV_SCALE (1.0f / 64.0f)
#define ROWB 32                                // fp4 row bytes (64 dims * 0.5 B)

// Scratch as device globals (pattern passed R2..R8).
__device__ unsigned char g_hf4[2][(size_t)N_NODES * ROWB]; // fp4 ping-pong h (scaled), 2x3.2MB
__device__ float g_sums[(size_t)3 * BATCH * DIM];  // sampled-row accumulators (f32)
__device__ int   g_cnt[N_NODES];                   // in-degree counts
__device__ int   g_fill[N_NODES];                  // CSR fill cursors
__device__ int   g_row_ptr[N_NODES + 1];           // CSR row offsets (by dst)
__device__ int   g_partials[SCAN_BLOCKS];          // scan partials
__device__ float g_dinv[N_NODES];                  // deg^-0.5
__device__ int2  g_csr[1280000];                   // packed (src, w-bits) per edge
__device__ float g_part_sp[BATCH];                 // per-wave softplus partials
__device__ float g_part_rg[BATCH];                 // per-wave reg partials

// ---- fp4 e2m1 helpers (value set 0,.5,1,1.5,2,3,4,6, signed) ----
__device__ inline float fp4_to_f32(unsigned int n) {        // n in [0,15]
    unsigned int s = n >> 3, em = n & 7;
    unsigned int bits;
    if (em < 2) bits = em ? 0x3F000000u : 0u;                // 0 or 0.5
    else        bits = ((126u + (em >> 1)) << 23) | ((em & 1) << 22);
    bits |= s << 31;
    return __uint_as_float(bits);
}
__device__ inline unsigned int f32_to_fp4(float f) {        // round to nearest
    unsigned int s = (__float_as_uint(f) >> 31) & 1u;
    float y = fabsf(f);
    unsigned int em;
    if      (y < 0.25f) em = 0;
    else if (y < 0.75f) em = 1;
    else if (y < 1.25f) em = 2;
    else if (y < 1.75f) em = 3;
    else if (y < 2.5f)  em = 4;
    else if (y < 3.5f)  em = 5;
    else if (y < 5.0f)  em = 6;
    else                em = 7;
    return (s << 3) | em;
}

// ---- zero the small per-call state ----
__global__ void zero_small() {
    size_t i = (size_t)blockIdx.x * blockDim.x + threadIdx.x;
    size_t stride = (size_t)gridDim.x * blockDim.x;
    for (size_t k = i; k < (size_t)3 * BATCH * DIM; k += stride) g_sums[k] = 0.0f;
    for (size_t k = i; k < N_NODES; k += stride) { g_cnt[k] = 0; g_fill[k] = 0; }
}

// ---- degree count (int atomics over 100k addresses: low per-line contention) ----
__global__ void count_deg(const int* __restrict__ dst, int E) {
    int e = blockIdx.x * blockDim.x + threadIdx.x;
    if (e < E) atomicAdd(&g_cnt[dst[e]], 1);
}

// ---- dinv from counts ----
__global__ void make_dinv() {
    int v = blockIdx.x * blockDim.x + threadIdx.x;
    if (v < N_NODES) {
        int c = g_cnt[v];
        g_dinv[v] = (c > 0) ? rsqrtf((float)c) : 0.0f;
    }
}

// ---- exclusive scan of g_cnt -> g_row_ptr, 3 phases ----
__global__ void scan_blocks() {
    __shared__ int sm[256];
    int i = blockIdx.x * 256 + threadIdx.x;
    int v = (i < N_NODES) ? g_cnt[i] : 0;
    sm[threadIdx.x] = v;
    __syncthreads();
    for (int off = 1; off < 256; off <<= 1) {
        int t = (threadIdx.x >= off) ? sm[threadIdx.x - off] : 0;
        __syncthreads();
        sm[threadIdx.x] += t;
        __syncthreads();
    }
    if (i < N_NODES) g_row_ptr[i] = sm[threadIdx.x] - v;  // exclusive
    if (threadIdx.x == 255) g_partials[blockIdx.x] = sm[255];
}

__global__ void scan_partials_fast(int E) {
    __shared__ int sm[512];
    int t = threadIdx.x;
    int v = (t < SCAN_BLOCKS) ? g_partials[t] : 0;
    sm[t] = v;
    __syncthreads();
    for (int off = 1; off < 512; off <<= 1) {
        int x = (t >= off) ? sm[t - off] : 0;
        __syncthreads();
        sm[t] += x;
        __syncthreads();
    }
    if (t < SCAN_BLOCKS) g_partials[t] = sm[t] - v;  // exclusive
    if (t == 0) g_row_ptr[N_NODES] = E;
}

__global__ void scan_add() {
    int i = blockIdx.x * 256 + threadIdx.x;
    if (i < N_NODES) g_row_ptr[i] += g_partials[blockIdx.x];
}

// ---- CSR fill: one thread per edge, single packed 8B store (R7 version) ----
__global__ void fill_csr(const int* __restrict__ src, const int* __restrict__ dst, int E) {
    int e = blockIdx.x * blockDim.x + threadIdx.x;
    if (e >= E) return;
    int s = src[e], d = dst[e];
    int pos = g_row_ptr[d] + atomicAdd(&g_fill[d], 1);
    float w = g_dinv[s] * g_dinv[d];
    g_csr[pos] = make_int2(s, __float_as_int(w));
}

// ---- convert emb (f32) to scaled fp4: one thread per output byte (2 dims) ----
__global__ void emb_to_fp4(const float* __restrict__ emb, unsigned char* __restrict__ hf) {
    size_t i = (size_t)blockIdx.x * blockDim.x + threadIdx.x;
    size_t stride = (size_t)gridDim.x * blockDim.x;
    for (size_t k = i; k < (size_t)N_NODES * ROWB; k += stride) {
        size_t node = k / ROWB;
        int    bi   = (int)(k % ROWB);
        float e0 = emb[node * DIM + 2 * bi]     * H_SCALE;
        float e1 = emb[node * DIM + 2 * bi + 1] * H_SCALE;
        hf[k] = (unsigned char)(f32_to_fp4(e0) | (f32_to_fp4(e1) << 4));
    }
}

// ---- pull one layer (fp4 scaled domain, f32 acc): wave per dst, 4-way unroll ----
__global__ void pull_layer_fp4(const unsigned char* __restrict__ h,
                               unsigned char* __restrict__ hn) {
    int wid  = (blockIdx.x * blockDim.x + threadIdx.x) >> 6;
    int lane = threadIdx.x & 63;
    if (wid >= N_NODES) return;
    int byi = lane >> 1;                 // byte index in row
    int shf = (lane & 1) * 4;            // nibble shift (even dim = low nibble)
    int beg = g_row_ptr[wid], end = g_row_ptr[wid + 1];
    float acc = 0.0f;
    for (int base = beg; base < end; base += 64) {
        int k = base + lane;
        int s = 0; float w = 0.0f;
        if (k < end) { int2 ew = g_csr[k]; s = ew.x; w = __int_as_float(ew.y); }
        int cnt = min(64, end - base);
        int j = 0;
        for (; j + 4 <= cnt; j += 4) {   // 4 independent gathers in flight
            int   s0 = __shfl(s, j),     s1 = __shfl(s, j + 1);
            int   s2 = __shfl(s, j + 2), s3 = __shfl(s, j + 3);
            float w0 = __shfl(w, j),     w1 = __shfl(w, j + 1);
            float w2 = __shfl(w, j + 2), w3 = __shfl(w, j + 3);
            unsigned char b0 = h[(size_t)s0 * ROWB + byi];
            unsigned char b1 = h[(size_t)s1 * ROWB + byi];
            unsigned char b2 = h[(size_t)s2 * ROWB + byi];
            unsigned char b3 = h[(size_t)s3 * ROWB + byi];
            acc = fmaf(w0, fp4_to_f32((b0 >> shf) & 0xF), acc);
            acc = fmaf(w1, fp4_to_f32((b1 >> shf) & 0xF), acc);
            acc = fmaf(w2, fp4_to_f32((b2 >> shf) & 0xF), acc);
            acc = fmaf(w3, fp4_to_f32((b3 >> shf) & 0xF), acc);
        }
        for (; j < cnt; ++j) {
            int   ss = __shfl(s, j);
            float ww = __shfl(w, j);
            unsigned char b = h[(size_t)ss * ROWB + byi];
            acc = fmaf(ww, fp4_to_f32((b >> shf) & 0xF), acc);
        }
    }
    unsigned int nib = f32_to_fp4(acc);
    unsigned int hi  = __shfl_down(nib, 1);     // odd lane's nibble
    if (!(lane & 1))
        hn[(size_t)wid * ROWB + byi] = (unsigned char)(nib | (hi << 4));
}

// ---- final layer: pull ONLY the sampled rows, add into g_sums (unscale here) ----
__global__ void pull_sampled(const unsigned char* __restrict__ h,
                             const int* __restrict__ users, const int* __restrict__ pos,
                             const int* __restrict__ neg) {
    int wid  = (blockIdx.x * blockDim.x + threadIdx.x) >> 6;
    int lane = threadIdx.x & 63;
    if (wid >= 3 * BATCH) return;
    int which = wid / BATCH;
    int i     = wid - which * BATCH;
    const int* idx = (which == 0) ? users : ((which == 1) ? pos : neg);
    int node = idx[i];
    int byi = lane >> 1;
    int shf = (lane & 1) * 4;
    int beg = g_row_ptr[node], end = g_row_ptr[node + 1];
    float acc = 0.0f;
    for (int base = beg; base < end; base += 64) {
        int k = base + lane;
        int s = 0; float w = 0.0f;
        if (k < end) { int2 ew = g_csr[k]; s = ew.x; w = __int_as_float(ew.y); }
        int cnt = min(64, end - base);
        int j = 0;
        for (; j + 4 <= cnt; j += 4) {
            int   s0 = __shfl(s, j),     s1 = __shfl(s, j + 1);
            int   s2 = __shfl(s, j + 2), s3 = __shfl(s, j + 3);
            float w0 = __shfl(w, j),     w1 = __shfl(w, j + 1);
            float w2 = __shfl(w, j + 2), w3 = __shfl(w, j + 3);
            unsigned char b0 = h[(size_t)s0 * ROWB + byi];
            unsigned char b1 = h[(size_t)s1 * ROWB + byi];
            unsigned char b2 = h[(size_t)s2 * ROWB + byi];
            unsigned char b3 = h[(size_t)s3 * ROWB + byi];
            acc = fmaf(w0, fp4_to_f32((b0 >> shf) & 0xF), acc);
            acc = fmaf(w1, fp4_to_f32((b1 >> shf) & 0xF), acc);
            acc = fmaf(w2, fp4_to_f32((b2 >> shf) & 0xF), acc);
            acc = fmaf(w3, fp4_to_f32((b3 >> shf) & 0xF), acc);
        }
        for (; j < cnt; ++j) {
            int   ss = __shfl(s, j);
            float ww = __shfl(w, j);
            unsigned char b = h[(size_t)ss * ROWB + byi];
            acc = fmaf(ww, fp4_to_f32((b >> shf) & 0xF), acc);
        }
    }
    g_sums[(size_t)wid * DIM + lane] += acc * H_INV_SCALE;  // wid owns row; no atomics
}

// ---- gather sampled rows (f32 source: layer 0 = emb) ----
__global__ void gather_acc_f32(const float* __restrict__ h,
                               const int* __restrict__ users, const int* __restrict__ pos,
                               const int* __restrict__ neg) {
    int wid  = (blockIdx.x * blockDim.x + threadIdx.x) >> 6;
    int lane = threadIdx.x & 63;
    if (wid >= 3 * BATCH) return;
    int which = wid / BATCH;
    int i     = wid - which * BATCH;
    const int* idx = (which == 0) ? users : ((which == 1) ? pos : neg);
    int node = idx[i];
    g_sums[(size_t)wid * DIM + lane] += h[(size_t)node * DIM + lane];
}

// ---- gather sampled rows (fp4 scaled source: layers 1,2) ----
__global__ void gather_acc_fp4(const unsigned char* __restrict__ h,
                               const int* __restrict__ users, const int* __restrict__ pos,
                               const int* __restrict__ neg) {
    int wid  = (blockIdx.x * blockDim.x + threadIdx.x) >> 6;
    int lane = threadIdx.x & 63;
    if (wid >= 3 * BATCH) return;
    int which = wid / BATCH;
    int i     = wid - which * BATCH;
    const int* idx = (which == 0) ? users : ((which == 1) ? pos : neg);
    int node = idx[i];
    unsigned char b = h[(size_t)node * ROWB + (lane >> 1)];
    float v = fp4_to_f32((b >> ((lane & 1) * 4)) & 0xF);
    g_sums[(size_t)wid * DIM + lane] += v * H_INV_SCALE;
}

// ---- per-sample scores + reg partials, wave-64 reduce, partials to arrays (NO atomics) ----
__global__ void score_reduce(const float* __restrict__ emb,
                             const int* __restrict__ users, const int* __restrict__ pos,
                             const int* __restrict__ neg) {
    int wid  = (blockIdx.x * blockDim.x + threadIdx.x) >> 6;
    int lane = threadIdx.x & 63;
    if (wid >= BATCH) return;
    float u = 0.25f * g_sums[(size_t)wid * DIM + lane];
    float p = 0.25f * g_sums[(size_t)(BATCH + wid) * DIM + lane];
    float n = 0.25f * g_sums[(size_t)(2 * BATCH + wid) * DIM + lane];
    float ps = u * p;
    float ns = u * n;
    float u0 = emb[(size_t)users[wid] * DIM + lane];
    float p0 = emb[(size_t)pos[wid]   * DIM + lane];
    float n0 = emb[(size_t)neg[wid]   * DIM + lane];
    float rg = u0 * u0 + p0 * p0 + n0 * n0;
    #pragma unroll
    for (int off = 32; off > 0; off >>= 1) {
        ps += __shfl_down(ps, off);
        ns += __shfl_down(ns, off);
        rg += __shfl_down(rg, off);
    }
    if (lane == 0) {
        float x  = ns - ps;
        float sp = fmaxf(x, 0.0f) + log1pf(expf(-fabsf(x)));  // stable softplus
        g_part_sp[wid] = sp;
        g_part_rg[wid] = rg;
    }
}

// ---- single-block final reduction over the 4096 per-wave partials ----
__global__ void final_reduce(float* __restrict__ out) {
    __shared__ float s_sp[256], s_rg[256];
    int t = threadIdx.x;
    float sp = 0.0f, rg = 0.0f;
    for (int i = t; i < BATCH; i += 256) { sp += g_part_sp[i]; rg += g_part_rg[i]; }
    s_sp[t] = sp; s_rg[t] = rg;
    __syncthreads();
    for (int off = 128; off > 0; off >>= 1) {
        if (t < off) { s_sp[t] += s_sp[t + off]; s_rg[t] += s_rg[t + off]; }
        __syncthreads();
    }
    if (t == 0) {
        float loss_emb = s_sp[0] / (float)BATCH;
        float reg      = 0.5f * s_rg[0] / (float)BATCH * REG_WEIGHT;
        out[0] = loss_emb + reg;
        out[1] = loss_emb;
        out[2] = reg;
    }
}

extern "C" void kernel_launch(void* const* d_in, const int* in_sizes, int n_in,
                              void* d_out, int out_size, void* d_ws, size_t ws_size,
                              hipStream_t stream) {
    const float* emb   = (const float*)d_in[0];
    const int*   src   = (const int*)d_in[1];
    const int*   dst   = (const int*)d_in[2];
    const int*   users = (const int*)d_in[3];
    const int*   pos   = (const int*)d_in[4];
    const int*   neg   = (const int*)d_in[5];
    const int E = in_sizes[1];
    float* out = (float*)d_out;

    unsigned char* hf_a;  hipGetSymbolAddress((void**)&hf_a, HIP_SYMBOL(g_hf4));
    unsigned char* hf_b = hf_a + (size_t)N_NODES * ROWB;

    zero_small<<<1024, 256, 0, stream>>>();
    count_deg<<<(E + 255) / 256, 256, 0, stream>>>(dst, E);
    make_dinv<<<(N_NODES + 255) / 256, 256, 0, stream>>>();

    scan_blocks<<<SCAN_BLOCKS, 256, 0, stream>>>();
    scan_partials_fast<<<1, 512, 0, stream>>>(E);
    scan_add<<<SCAN_BLOCKS, 256, 0, stream>>>();
    fill_csr<<<(E + 255) / 256, 256, 0, stream>>>(src, dst, E);

    emb_to_fp4<<<2048, 256, 0, stream>>>(emb, hf_a);

    // layer 0 contribution (emb itself, f32)
    gather_acc_f32<<<(3 * BATCH * 64 + 255) / 256, 256, 0, stream>>>(emb, users, pos, neg);

    // layer 1: full pull (needed as input to layer 2)
    pull_layer_fp4<<<(N_NODES * 64 + 255) / 256, 256, 0, stream>>>(hf_a, hf_b);
    gather_acc_fp4<<<(3 * BATCH * 64 + 255) / 256, 256, 0, stream>>>(hf_b, users, pos, neg);

    // layer 2: full pull (needed as input to layer 3's sampled pull)
    pull_layer_fp4<<<(N_NODES * 64 + 255) / 256, 256, 0, stream>>>(hf_b, hf_a);
    gather_acc_fp4<<<(3 * BATCH * 64 + 255) / 256, 256, 0, stream>>>(hf_a, users, pos, neg);

    // layer 3: only the 3*BATCH sampled rows are ever read — pull just those
    pull_sampled<<<(3 * BATCH * 64 + 255) / 256, 256, 0, stream>>>(hf_a, users, pos, neg);

    score_reduce<<<(BATCH * 64 + 255) / 256, 256, 0, stream>>>(emb, users, pos, neg);
    final_reduce<<<1, 256, 0, stream>>>(out);
}

// Round 10
// 314.222 us; speedup vs baseline: 1.6982x; 1.0793x over previous
//
#include <hip/hip_runtime.h>
#include <hip/hip_fp8.h>
#include <math.h>

#define N_NODES 100000
#define DIM 64
#define NUM_LAYER 3
#define BATCH 4096
#define REG_WEIGHT 1e-4f
#define SCAN_BLOCKS ((N_NODES + 255) / 256)   // 391
#define NBUCKET 391                            // dst >> 8 buckets (256 nodes each)
#define CURPAD 16                              // ints: 64B pad per bucket cursor
#define H_SCALE 64.0f
#define H_INV_SCALE (1.0f / 64.0f)

// Scratch as device globals (pattern passed R2..R9).
__device__ unsigned char g_hf8[2][(size_t)N_NODES * DIM]; // fp8 ping-pong h (scaled)
__device__ float g_sums[(size_t)3 * BATCH * DIM];  // sampled-row accumulators (f32)
__device__ int   g_cnt[N_NODES];                   // in-degree counts
__device__ int   g_fill[N_NODES];                  // CSR fill cursors
__device__ int   g_row_ptr[N_NODES + 1];           // CSR row offsets (by dst)
__device__ int   g_partials[SCAN_BLOCKS];          // scan partials
__device__ float g_dinv[N_NODES];                  // deg^-0.5
__device__ int   g_bcur[NBUCKET * CURPAD];         // padded bucket staging cursors
__device__ int2  g_stage[1280000];                 // staged (src, dst), bucket-grouped
__device__ int2  g_csr[1280000];                   // final packed (src, w-bits) per edge
__device__ float g_part_sp[BATCH];                 // per-wave softplus partials
__device__ float g_part_rg[BATCH];                 // per-wave reg partials

__device__ inline float fp8_to_f32(unsigned char v) {
    __hip_fp8_e4m3 t; t.__x = (__hip_fp8_storage_t)v; return (float)t;
}
__device__ inline unsigned char f32_to_fp8(float f) {
    __hip_fp8_e4m3 t(f); return (unsigned char)t.__x;
}

// ---- zero the small per-call state ----
__global__ void zero_small() {
    size_t i = (size_t)blockIdx.x * blockDim.x + threadIdx.x;
    size_t stride = (size_t)gridDim.x * blockDim.x;
    for (size_t k = i; k < (size_t)3 * BATCH * DIM; k += stride) g_sums[k] = 0.0f;
    for (size_t k = i; k < N_NODES; k += stride) { g_cnt[k] = 0; g_fill[k] = 0; }
}

// ---- degree count (int atomics over 100k addresses: low per-line contention) ----
__global__ void count_deg(const int* __restrict__ dst, int E) {
    int e = blockIdx.x * blockDim.x + threadIdx.x;
    if (e < E) atomicAdd(&g_cnt[dst[e]], 1);
}

// ---- dinv from counts ----
__global__ void make_dinv() {
    int v = blockIdx.x * blockDim.x + threadIdx.x;
    if (v < N_NODES) {
        int c = g_cnt[v];
        g_dinv[v] = (c > 0) ? rsqrtf((float)c) : 0.0f;
    }
}

// ---- exclusive scan of g_cnt -> g_row_ptr, 3 phases ----
__global__ void scan_blocks() {
    __shared__ int sm[256];
    int i = blockIdx.x * 256 + threadIdx.x;
    int v = (i < N_NODES) ? g_cnt[i] : 0;
    sm[threadIdx.x] = v;
    __syncthreads();
    for (int off = 1; off < 256; off <<= 1) {
        int t = (threadIdx.x >= off) ? sm[threadIdx.x - off] : 0;
        __syncthreads();
        sm[threadIdx.x] += t;
        __syncthreads();
    }
    if (i < N_NODES) g_row_ptr[i] = sm[threadIdx.x] - v;  // exclusive
    if (threadIdx.x == 255) g_partials[blockIdx.x] = sm[255];
}

__global__ void scan_partials_fast(int E) {
    __shared__ int sm[512];
    int t = threadIdx.x;
    int v = (t < SCAN_BLOCKS) ? g_partials[t] : 0;
    sm[t] = v;
    __syncthreads();
    for (int off = 1; off < 512; off <<= 1) {
        int x = (t >= off) ? sm[t - off] : 0;
        __syncthreads();
        sm[t] += x;
        __syncthreads();
    }
    if (t < SCAN_BLOCKS) g_partials[t] = sm[t] - v;  // exclusive
    if (t == 0) g_row_ptr[N_NODES] = E;
}

__global__ void scan_add() {
    int i = blockIdx.x * 256 + threadIdx.x;
    if (i < N_NODES) g_row_ptr[i] += g_partials[blockIdx.x];
}

// ---- init padded bucket cursors to bucket base offsets ----
__global__ void init_bcur() {
    int i = blockIdx.x * blockDim.x + threadIdx.x;
    if (i < NBUCKET) g_bcur[i * CURPAD] = g_row_ptr[i << 8];
}

// ---- stage pass: LDS histogram per block -> few padded global reservations ->
//      per-block sequential-run stores into bucket staging regions ----
#define EDGES_PER_THREAD 8
__global__ void __launch_bounds__(1024) stage_buckets(const int* __restrict__ src,
                                                      const int* __restrict__ dst, int E) {
    __shared__ int h[NBUCKET];
    __shared__ int cur[NBUCKET];
    int tid = threadIdx.x;
    int base = blockIdx.x * (1024 * EDGES_PER_THREAD);
    for (int i = tid; i < NBUCKET; i += 1024) h[i] = 0;
    __syncthreads();
    int myd[EDGES_PER_THREAD], mys[EDGES_PER_THREAD];
    #pragma unroll
    for (int k = 0; k < EDGES_PER_THREAD; ++k) {
        int e = base + k * 1024 + tid;
        if (e < E) {
            myd[k] = dst[e]; mys[k] = src[e];
            atomicAdd(&h[myd[k] >> 8], 1);
        } else myd[k] = -1;
    }
    __syncthreads();
    for (int i = tid; i < NBUCKET; i += 1024) {
        int c = h[i];
        cur[i] = c ? atomicAdd(&g_bcur[i * CURPAD], c) : 0;  // reserve run in bucket region
    }
    __syncthreads();
    #pragma unroll
    for (int k = 0; k < EDGES_PER_THREAD; ++k) {
        if (myd[k] >= 0) {
            int p = atomicAdd(&cur[myd[k] >> 8], 1);          // LDS cursor -> slot
            g_stage[p] = make_int2(mys[k], myd[k]);
        }
    }
}

// ---- bucket sort: one block per bucket; all stores land in the block's 26 KB CSR window ----
__global__ void bucket_sort() {
    int b = blockIdx.x;
    int beg  = g_row_ptr[b << 8];
    int endn = min(N_NODES, (b + 1) << 8);
    int end  = g_row_ptr[endn];
    for (int k = beg + threadIdx.x; k < end; k += blockDim.x) {
        int2 sd = g_stage[k];
        int s = sd.x, d = sd.y;
        int pos = g_row_ptr[d] + atomicAdd(&g_fill[d], 1);
        float w = g_dinv[s] * g_dinv[d];
        g_csr[pos] = make_int2(s, __float_as_int(w));
    }
}

// ---- convert emb (f32) to scaled fp8 ----
__global__ void emb_to_fp8(const float* __restrict__ emb, unsigned char* __restrict__ hf) {
    size_t i = (size_t)blockIdx.x * blockDim.x + threadIdx.x;
    size_t stride = (size_t)gridDim.x * blockDim.x;
    for (size_t k = i; k < (size_t)N_NODES * DIM; k += stride)
        hf[k] = f32_to_fp8(emb[k] * H_SCALE);
}

// ---- pull one layer (fp8 scaled domain, f32 acc): wave per dst, 4-way unroll ----
__global__ void pull_layer_fp8(const unsigned char* __restrict__ h,
                               unsigned char* __restrict__ hn) {
    int wid  = (blockIdx.x * blockDim.x + threadIdx.x) >> 6;
    int lane = threadIdx.x & 63;
    if (wid >= N_NODES) return;
    int beg = g_row_ptr[wid], end = g_row_ptr[wid + 1];
    float acc = 0.0f;
    for (int base = beg; base < end; base += 64) {
        int k = base + lane;
        int s = 0; float w = 0.0f;
        if (k < end) { int2 ew = g_csr[k]; s = ew.x; w = __int_as_float(ew.y); }
        int cnt = min(64, end - base);
        int j = 0;
        for (; j + 4 <= cnt; j += 4) {   // 4 independent gathers in flight
            int   s0 = __shfl(s, j),     s1 = __shfl(s, j + 1);
            int   s2 = __shfl(s, j + 2), s3 = __shfl(s, j + 3);
            float w0 = __shfl(w, j),     w1 = __shfl(w, j + 1);
            float w2 = __shfl(w, j + 2), w3 = __shfl(w, j + 3);
            float h0 = fp8_to_f32(h[(size_t)s0 * DIM + lane]);
            float h1 = fp8_to_f32(h[(size_t)s1 * DIM + lane]);
            float h2 = fp8_to_f32(h[(size_t)s2 * DIM + lane]);
            float h3 = fp8_to_f32(h[(size_t)s3 * DIM + lane]);
            acc = fmaf(w0, h0, acc); acc = fmaf(w1, h1, acc);
            acc = fmaf(w2, h2, acc); acc = fmaf(w3, h3, acc);
        }
        for (; j < cnt; ++j) {
            int   ss = __shfl(s, j);
            float ww = __shfl(w, j);
            acc = fmaf(ww, fp8_to_f32(h[(size_t)ss * DIM + lane]), acc);
        }
    }
    hn[(size_t)wid * DIM + lane] = f32_to_fp8(acc);
}

// ---- final layer: pull ONLY the sampled rows, add into g_sums (unscale here) ----
__global__ void pull_sampled(const unsigned char* __restrict__ h,
                             const int* __restrict__ users, const int* __restrict__ pos,
                             const int* __restrict__ neg) {
    int wid  = (blockIdx.x * blockDim.x + threadIdx.x) >> 6;
    int lane = threadIdx.x & 63;
    if (wid >= 3 * BATCH) return;
    int which = wid / BATCH;
    int i     = wid - which * BATCH;
    const int* idx = (which == 0) ? users : ((which == 1) ? pos : neg);
    int node = idx[i];
    int beg = g_row_ptr[node], end = g_row_ptr[node + 1];
    float acc = 0.0f;
    for (int base = beg; base < end; base += 64) {
        int k = base + lane;
        int s = 0; float w = 0.0f;
        if (k < end) { int2 ew = g_csr[k]; s = ew.x; w = __int_as_float(ew.y); }
        int cnt = min(64, end - base);
        int j = 0;
        for (; j + 4 <= cnt; j += 4) {
            int   s0 = __shfl(s, j),     s1 = __shfl(s, j + 1);
            int   s2 = __shfl(s, j + 2), s3 = __shfl(s, j + 3);
            float w0 = __shfl(w, j),     w1 = __shfl(w, j + 1);
            float w2 = __shfl(w, j + 2), w3 = __shfl(w, j + 3);
            float h0 = fp8_to_f32(h[(size_t)s0 * DIM + lane]);
            float h1 = fp8_to_f32(h[(size_t)s1 * DIM + lane]);
            float h2 = fp8_to_f32(h[(size_t)s2 * DIM + lane]);
            float h3 = fp8_to_f32(h[(size_t)s3 * DIM + lane]);
            acc = fmaf(w0, h0, acc); acc = fmaf(w1, h1, acc);
            acc = fmaf(w2, h2, acc); acc = fmaf(w3, h3, acc);
        }
        for (; j < cnt; ++j) {
            int   ss = __shfl(s, j);
            float ww = __shfl(w, j);
            acc = fmaf(ww, fp8_to_f32(h[(size_t)ss * DIM + lane]), acc);
        }
    }
    g_sums[(size_t)wid * DIM + lane] += acc * H_INV_SCALE;  // wid owns row; no atomics
}

// ---- gather sampled rows (f32 source: layer 0 = emb) ----
__global__ void gather_acc_f32(const float* __restrict__ h,
                               const int* __restrict__ users, const int* __restrict__ pos,
                               const int* __restrict__ neg) {
    int wid  = (blockIdx.x * blockDim.x + threadIdx.x) >> 6;
    int lane = threadIdx.x & 63;
    if (wid >= 3 * BATCH) return;
    int which = wid / BATCH;
    int i     = wid - which * BATCH;
    const int* idx = (which == 0) ? users : ((which == 1) ? pos : neg);
    int node = idx[i];
    g_sums[(size_t)wid * DIM + lane] += h[(size_t)node * DIM + lane];
}

// ---- gather sampled rows (fp8 scaled source: layers 1,2) ----
__global__ void gather_acc_fp8(const unsigned char* __restrict__ h,
                               const int* __restrict__ users, const int* __restrict__ pos,
                               const int* __restrict__ neg) {
    int wid  = (blockIdx.x * blockDim.x + threadIdx.x) >> 6;
    int lane = threadIdx.x & 63;
    if (wid >= 3 * BATCH) return;
    int which = wid / BATCH;
    int i     = wid - which * BATCH;
    const int* idx = (which == 0) ? users : ((which == 1) ? pos : neg);
    int node = idx[i];
    g_sums[(size_t)wid * DIM + lane] += fp8_to_f32(h[(size_t)node * DIM + lane]) * H_INV_SCALE;
}

// ---- per-sample scores + reg partials, wave-64 reduce, partials to arrays (NO atomics) ----
__global__ void score_reduce(const float* __restrict__ emb,
                             const int* __restrict__ users, const int* __restrict__ pos,
                             const int* __restrict__ neg) {
    int wid  = (blockIdx.x * blockDim.x + threadIdx.x) >> 6;
    int lane = threadIdx.x & 63;
    if (wid >= BATCH) return;
    float u = 0.25f * g_sums[(size_t)wid * DIM + lane];
    float p = 0.25f * g_sums[(size_t)(BATCH + wid) * DIM + lane];
    float n = 0.25f * g_sums[(size_t)(2 * BATCH + wid) * DIM + lane];
    float ps = u * p;
    float ns = u * n;
    float u0 = emb[(size_t)users[wid] * DIM + lane];
    float p0 = emb[(size_t)pos[wid]   * DIM + lane];
    float n0 = emb[(size_t)neg[wid]   * DIM + lane];
    float rg = u0 * u0 + p0 * p0 + n0 * n0;
    #pragma unroll
    for (int off = 32; off > 0; off >>= 1) {
        ps += __shfl_down(ps, off);
        ns += __shfl_down(ns, off);
        rg += __shfl_down(rg, off);
    }
    if (lane == 0) {
        float x  = ns - ps;
        float sp = fmaxf(x, 0.0f) + log1pf(expf(-fabsf(x)));  // stable softplus
        g_part_sp[wid] = sp;
        g_part_rg[wid] = rg;
    }
}

// ---- single-block final reduction over the 4096 per-wave partials ----
__global__ void final_reduce(float* __restrict__ out) {
    __shared__ float s_sp[256], s_rg[256];
    int t = threadIdx.x;
    float sp = 0.0f, rg = 0.0f;
    for (int i = t; i < BATCH; i += 256) { sp += g_part_sp[i]; rg += g_part_rg[i]; }
    s_sp[t] = sp; s_rg[t] = rg;
    __syncthreads();
    for (int off = 128; off > 0; off >>= 1) {
        if (t < off) { s_sp[t] += s_sp[t + off]; s_rg[t] += s_rg[t + off]; }
        __syncthreads();
    }
    if (t == 0) {
        float loss_emb = s_sp[0] / (float)BATCH;
        float reg      = 0.5f * s_rg[0] / (float)BATCH * REG_WEIGHT;
        out[0] = loss_emb + reg;
        out[1] = loss_emb;
        out[2] = reg;
    }
}

extern "C" void kernel_launch(void* const* d_in, const int* in_sizes, int n_in,
                              void* d_out, int out_size, void* d_ws, size_t ws_size,
                              hipStream_t stream) {
    const float* emb   = (const float*)d_in[0];
    const int*   src   = (const int*)d_in[1];
    const int*   dst   = (const int*)d_in[2];
    const int*   users = (const int*)d_in[3];
    const int*   pos   = (const int*)d_in[4];
    const int*   neg   = (const int*)d_in[5];
    const int E = in_sizes[1];
    float* out = (float*)d_out;

    unsigned char* hf_a;  hipGetSymbolAddress((void**)&hf_a, HIP_SYMBOL(g_hf8));
    unsigned char* hf_b = hf_a + (size_t)N_NODES * DIM;

    zero_small<<<1024, 256, 0, stream>>>();
    count_deg<<<(E + 255) / 256, 256, 0, stream>>>(dst, E);
    make_dinv<<<(N_NODES + 255) / 256, 256, 0, stream>>>();

    scan_blocks<<<SCAN_BLOCKS, 256, 0, stream>>>();
    scan_partials_fast<<<1, 512, 0, stream>>>(E);
    scan_add<<<SCAN_BLOCKS, 256, 0, stream>>>();

    init_bcur<<<(NBUCKET + 255) / 256, 256, 0, stream>>>();
    const int STAGE_BLOCKS = (E + 1024 * EDGES_PER_THREAD - 1) / (1024 * EDGES_PER_THREAD);
    stage_buckets<<<STAGE_BLOCKS, 1024, 0, stream>>>(src, dst, E);
    bucket_sort<<<NBUCKET, 256, 0, stream>>>();

    emb_to_fp8<<<2048, 256, 0, stream>>>(emb, hf_a);

    // layer 0 contribution (emb itself, f32)
    gather_acc_f32<<<(3 * BATCH * 64 + 255) / 256, 256, 0, stream>>>(emb, users, pos, neg);

    // layer 1: full pull (needed as input to layer 2)
    pull_layer_fp8<<<(N_NODES * 64 + 255) / 256, 256, 0, stream>>>(hf_a, hf_b);
    gather_acc_fp8<<<(3 * BATCH * 64 + 255) / 256, 256, 0, stream>>>(hf_b, users, pos, neg);

    // layer 2: full pull (needed as input to layer 3's sampled pull)
    pull_layer_fp8<<<(N_NODES * 64 + 255) / 256, 256, 0, stream>>>(hf_b, hf_a);
    gather_acc_fp8<<<(3 * BATCH * 64 + 255) / 256, 256, 0, stream>>>(hf_a, users, pos, neg);

    // layer 3: only the 3*BATCH sampled rows are ever read — pull just those
    pull_sampled<<<(3 * BATCH * 64 + 255) / 256, 256, 0, stream>>>(hf_a, users, pos, neg);

    score_reduce<<<(BATCH * 64 + 255) / 256, 256, 0, stream>>>(emb, users, pos, neg);
    final_reduce<<<1, 256, 0, stream>>>(out);
}

// Round 11
// 246.627 us; speedup vs baseline: 2.1637x; 1.2741x over previous
//
#include <hip/hip_runtime.h>
#include <hip/hip_fp8.h>
#include <math.h>

#define N_NODES 100000
#define DIM 64
#define NUM_LAYER 3
#define BATCH 4096
#define REG_WEIGHT 1e-4f
#define NBUCKET 391                            // dst >> 8 buckets (256 nodes each)
#define STAGE_CAP 4096                         // fixed staging capacity per bucket
#define CURPAD 16                              // ints: 64B pad per bucket cursor
#define H_SCALE 64.0f
#define H_INV_SCALE (1.0f / 64.0f)

// Scratch as device globals (pattern passed R2..R10).
__device__ unsigned char g_hf8[2][(size_t)N_NODES * DIM]; // fp8 ping-pong h (scaled)
__device__ float g_sums[(size_t)3 * BATCH * DIM];  // sampled-row accumulators (f32)
__device__ int   g_row_ptr[N_NODES + 1];           // CSR row offsets (by dst)
__device__ float g_dinv[N_NODES];                  // deg^-0.5
__device__ int   g_bcur[NBUCKET * CURPAD];         // padded bucket staging cursors
__device__ int   g_bbase[NBUCKET];                 // bucket base offsets in CSR
__device__ int2  g_stage[NBUCKET * STAGE_CAP];     // staged (src, dst), fixed-cap regions
__device__ int2  g_csr[1280000];                   // final packed (src, w-bits) per edge
__device__ float g_part_sp[BATCH];                 // per-wave softplus partials
__device__ float g_part_rg[BATCH];                 // per-wave reg partials

__device__ inline float fp8_to_f32(unsigned char v) {
    __hip_fp8_e4m3 t; t.__x = (__hip_fp8_storage_t)v; return (float)t;
}
__device__ inline unsigned char f32_to_fp8(float f) {
    __hip_fp8_e4m3 t(f); return (unsigned char)t.__x;
}

// ---- zero g_sums; init padded bucket cursors to fixed-region bases ----
__global__ void zero_small() {
    size_t i = (size_t)blockIdx.x * blockDim.x + threadIdx.x;
    size_t stride = (size_t)gridDim.x * blockDim.x;
    for (size_t k = i; k < (size_t)3 * BATCH * DIM; k += stride) g_sums[k] = 0.0f;
    for (size_t k = i; k < NBUCKET; k += stride) g_bcur[k * CURPAD] = (int)k * STAGE_CAP;
}

// ---- stage pass: LDS histogram per block -> few padded global reservations ->
//      per-block sequential-run stores into fixed-cap bucket staging regions ----
#define EDGES_PER_THREAD 8
__global__ void __launch_bounds__(1024) stage_buckets(const int* __restrict__ src,
                                                      const int* __restrict__ dst, int E) {
    __shared__ int h[NBUCKET];
    __shared__ int cur[NBUCKET];
    int tid = threadIdx.x;
    int base = blockIdx.x * (1024 * EDGES_PER_THREAD);
    for (int i = tid; i < NBUCKET; i += 1024) h[i] = 0;
    __syncthreads();
    int myd[EDGES_PER_THREAD], mys[EDGES_PER_THREAD];
    #pragma unroll
    for (int k = 0; k < EDGES_PER_THREAD; ++k) {
        int e = base + k * 1024 + tid;
        if (e < E) {
            myd[k] = dst[e]; mys[k] = src[e];
            atomicAdd(&h[myd[k] >> 8], 1);
        } else myd[k] = -1;
    }
    __syncthreads();
    for (int i = tid; i < NBUCKET; i += 1024) {
        int c = h[i];
        cur[i] = c ? atomicAdd(&g_bcur[i * CURPAD], c) : 0;  // reserve run in bucket region
    }
    __syncthreads();
    #pragma unroll
    for (int k = 0; k < EDGES_PER_THREAD; ++k) {
        if (myd[k] >= 0) {
            int p = atomicAdd(&cur[myd[k] >> 8], 1);          // LDS cursor -> slot
            g_stage[p] = make_int2(mys[k], myd[k]);
        }
    }
}

// ---- single-block exclusive scan of the 391 bucket totals -> CSR bucket bases ----
__global__ void btotals_scan(int E) {
    __shared__ int sm[512];
    int t = threadIdx.x;
    int c = (t < NBUCKET) ? (g_bcur[t * CURPAD] - t * STAGE_CAP) : 0;
    sm[t] = c;
    __syncthreads();
    for (int off = 1; off < 512; off <<= 1) {
        int x = (t >= off) ? sm[t - off] : 0;
        __syncthreads();
        sm[t] += x;
        __syncthreads();
    }
    if (t < NBUCKET) g_bbase[t] = sm[t] - c;   // exclusive
    if (t == 0) g_row_ptr[N_NODES] = E;
}

// ---- per-bucket: LDS degree hist + scan -> row_ptr & dinv (NO global atomics) ----
__global__ void bucket_finalize() {
    __shared__ int lh[256];
    __shared__ int sc[256];
    int b = blockIdx.x, t = threadIdx.x;
    int cnt  = g_bcur[b * CURPAD] - b * STAGE_CAP;
    int sbeg = b * STAGE_CAP;
    lh[t] = 0;
    __syncthreads();
    for (int k = t; k < cnt; k += 256)
        atomicAdd(&lh[g_stage[sbeg + k].y & 255], 1);
    __syncthreads();
    int v = lh[t];
    sc[t] = v;
    __syncthreads();
    for (int off = 1; off < 256; off <<= 1) {
        int x = (t >= off) ? sc[t - off] : 0;
        __syncthreads();
        sc[t] += x;
        __syncthreads();
    }
    int node = (b << 8) + t;
    if (node < N_NODES) {
        g_row_ptr[node] = g_bbase[b] + sc[t] - v;            // exclusive
        g_dinv[node]    = (v > 0) ? rsqrtf((float)v) : 0.0f;
    }
}

// ---- per-bucket: scatter staged edges into the bucket's 26 KB CSR window ----
__global__ void bucket_place() {
    __shared__ int cur[256];
    int b = blockIdx.x, t = threadIdx.x;
    int cnt  = g_bcur[b * CURPAD] - b * STAGE_CAP;
    int sbeg = b * STAGE_CAP;
    int node = (b << 8) + t;
    cur[t] = (node < N_NODES) ? g_row_ptr[node] : 0;
    __syncthreads();
    for (int k = t; k < cnt; k += 256) {
        int2 sd = g_stage[sbeg + k];
        int pos = atomicAdd(&cur[sd.y & 255], 1);            // LDS cursor, block-local
        float w = g_dinv[sd.x] * g_dinv[sd.y];
        g_csr[pos] = make_int2(sd.x, __float_as_int(w));
    }
}

// ---- convert emb (f32) to scaled fp8 ----
__global__ void emb_to_fp8(const float* __restrict__ emb, unsigned char* __restrict__ hf) {
    size_t i = (size_t)blockIdx.x * blockDim.x + threadIdx.x;
    size_t stride = (size_t)gridDim.x * blockDim.x;
    for (size_t k = i; k < (size_t)N_NODES * DIM; k += stride)
        hf[k] = f32_to_fp8(emb[k] * H_SCALE);
}

// ---- pull one layer (fp8 scaled domain, f32 acc): wave per dst, 4-way unroll ----
__global__ void pull_layer_fp8(const unsigned char* __restrict__ h,
                               unsigned char* __restrict__ hn) {
    int wid  = (blockIdx.x * blockDim.x + threadIdx.x) >> 6;
    int lane = threadIdx.x & 63;
    if (wid >= N_NODES) return;
    int beg = g_row_ptr[wid], end = g_row_ptr[wid + 1];
    float acc = 0.0f;
    for (int base = beg; base < end; base += 64) {
        int k = base + lane;
        int s = 0; float w = 0.0f;
        if (k < end) { int2 ew = g_csr[k]; s = ew.x; w = __int_as_float(ew.y); }
        int cnt = min(64, end - base);
        int j = 0;
        for (; j + 4 <= cnt; j += 4) {   // 4 independent gathers in flight
            int   s0 = __shfl(s, j),     s1 = __shfl(s, j + 1);
            int   s2 = __shfl(s, j + 2), s3 = __shfl(s, j + 3);
            float w0 = __shfl(w, j),     w1 = __shfl(w, j + 1);
            float w2 = __shfl(w, j + 2), w3 = __shfl(w, j + 3);
            float h0 = fp8_to_f32(h[(size_t)s0 * DIM + lane]);
            float h1 = fp8_to_f32(h[(size_t)s1 * DIM + lane]);
            float h2 = fp8_to_f32(h[(size_t)s2 * DIM + lane]);
            float h3 = fp8_to_f32(h[(size_t)s3 * DIM + lane]);
            acc = fmaf(w0, h0, acc); acc = fmaf(w1, h1, acc);
            acc = fmaf(w2, h2, acc); acc = fmaf(w3, h3, acc);
        }
        for (; j < cnt; ++j) {
            int   ss = __shfl(s, j);
            float ww = __shfl(w, j);
            acc = fmaf(ww, fp8_to_f32(h[(size_t)ss * DIM + lane]), acc);
        }
    }
    hn[(size_t)wid * DIM + lane] = f32_to_fp8(acc);
}

// ---- final layer: pull ONLY the sampled rows, add into g_sums (unscale here) ----
__global__ void pull_sampled(const unsigned char* __restrict__ h,
                             const int* __restrict__ users, const int* __restrict__ pos,
                             const int* __restrict__ neg) {
    int wid  = (blockIdx.x * blockDim.x + threadIdx.x) >> 6;
    int lane = threadIdx.x & 63;
    if (wid >= 3 * BATCH) return;
    int which = wid / BATCH;
    int i     = wid - which * BATCH;
    const int* idx = (which == 0) ? users : ((which == 1) ? pos : neg);
    int node = idx[i];
    int beg = g_row_ptr[node], end = g_row_ptr[node + 1];
    float acc = 0.0f;
    for (int base = beg; base < end; base += 64) {
        int k = base + lane;
        int s = 0; float w = 0.0f;
        if (k < end) { int2 ew = g_csr[k]; s = ew.x; w = __int_as_float(ew.y); }
        int cnt = min(64, end - base);
        int j = 0;
        for (; j + 4 <= cnt; j += 4) {
            int   s0 = __shfl(s, j),     s1 = __shfl(s, j + 1);
            int   s2 = __shfl(s, j + 2), s3 = __shfl(s, j + 3);
            float w0 = __shfl(w, j),     w1 = __shfl(w, j + 1);
            float w2 = __shfl(w, j + 2), w3 = __shfl(w, j + 3);
            float h0 = fp8_to_f32(h[(size_t)s0 * DIM + lane]);
            float h1 = fp8_to_f32(h[(size_t)s1 * DIM + lane]);
            float h2 = fp8_to_f32(h[(size_t)s2 * DIM + lane]);
            float h3 = fp8_to_f32(h[(size_t)s3 * DIM + lane]);
            acc = fmaf(w0, h0, acc); acc = fmaf(w1, h1, acc);
            acc = fmaf(w2, h2, acc); acc = fmaf(w3, h3, acc);
        }
        for (; j < cnt; ++j) {
            int   ss = __shfl(s, j);
            float ww = __shfl(w, j);
            acc = fmaf(ww, fp8_to_f32(h[(size_t)ss * DIM + lane]), acc);
        }
    }
    g_sums[(size_t)wid * DIM + lane] += acc * H_INV_SCALE;  // wid owns row; no atomics
}

// ---- gather sampled rows (f32 source: layer 0 = emb) ----
__global__ void gather_acc_f32(const float* __restrict__ h,
                               const int* __restrict__ users, const int* __restrict__ pos,
                               const int* __restrict__ neg) {
    int wid  = (blockIdx.x * blockDim.x + threadIdx.x) >> 6;
    int lane = threadIdx.x & 63;
    if (wid >= 3 * BATCH) return;
    int which = wid / BATCH;
    int i     = wid - which * BATCH;
    const int* idx = (which == 0) ? users : ((which == 1) ? pos : neg);
    int node = idx[i];
    g_sums[(size_t)wid * DIM + lane] += h[(size_t)node * DIM + lane];
}

// ---- gather sampled rows (fp8 scaled source: layers 1,2) ----
__global__ void gather_acc_fp8(const unsigned char* __restrict__ h,
                               const int* __restrict__ users, const int* __restrict__ pos,
                               const int* __restrict__ neg) {
    int wid  = (blockIdx.x * blockDim.x + threadIdx.x) >> 6;
    int lane = threadIdx.x & 63;
    if (wid >= 3 * BATCH) return;
    int which = wid / BATCH;
    int i     = wid - which * BATCH;
    const int* idx = (which == 0) ? users : ((which == 1) ? pos : neg);
    int node = idx[i];
    g_sums[(size_t)wid * DIM + lane] += fp8_to_f32(h[(size_t)node * DIM + lane]) * H_INV_SCALE;
}

// ---- per-sample scores + reg partials, wave-64 reduce, partials to arrays (NO atomics) ----
__global__ void score_reduce(const float* __restrict__ emb,
                             const int* __restrict__ users, const int* __restrict__ pos,
                             const int* __restrict__ neg) {
    int wid  = (blockIdx.x * blockDim.x + threadIdx.x) >> 6;
    int lane = threadIdx.x & 63;
    if (wid >= BATCH) return;
    float u = 0.25f * g_sums[(size_t)wid * DIM + lane];
    float p = 0.25f * g_sums[(size_t)(BATCH + wid) * DIM + lane];
    float n = 0.25f * g_sums[(size_t)(2 * BATCH + wid) * DIM + lane];
    float ps = u * p;
    float ns = u * n;
    float u0 = emb[(size_t)users[wid] * DIM + lane];
    float p0 = emb[(size_t)pos[wid]   * DIM + lane];
    float n0 = emb[(size_t)neg[wid]   * DIM + lane];
    float rg = u0 * u0 + p0 * p0 + n0 * n0;
    #pragma unroll
    for (int off = 32; off > 0; off >>= 1) {
        ps += __shfl_down(ps, off);
        ns += __shfl_down(ns, off);
        rg += __shfl_down(rg, off);
    }
    if (lane == 0) {
        float x  = ns - ps;
        float sp = fmaxf(x, 0.0f) + log1pf(expf(-fabsf(x)));  // stable softplus
        g_part_sp[wid] = sp;
        g_part_rg[wid] = rg;
    }
}

// ---- single-block final reduction over the 4096 per-wave partials ----
__global__ void final_reduce(float* __restrict__ out) {
    __shared__ float s_sp[256], s_rg[256];
    int t = threadIdx.x;
    float sp = 0.0f, rg = 0.0f;
    for (int i = t; i < BATCH; i += 256) { sp += g_part_sp[i]; rg += g_part_rg[i]; }
    s_sp[t] = sp; s_rg[t] = rg;
    __syncthreads();
    for (int off = 128; off > 0; off >>= 1) {
        if (t < off) { s_sp[t] += s_sp[t + off]; s_rg[t] += s_rg[t + off]; }
        __syncthreads();
    }
    if (t == 0) {
        float loss_emb = s_sp[0] / (float)BATCH;
        float reg      = 0.5f * s_rg[0] / (float)BATCH * REG_WEIGHT;
        out[0] = loss_emb + reg;
        out[1] = loss_emb;
        out[2] = reg;
    }
}

extern "C" void kernel_launch(void* const* d_in, const int* in_sizes, int n_in,
                              void* d_out, int out_size, void* d_ws, size_t ws_size,
                              hipStream_t stream) {
    const float* emb   = (const float*)d_in[0];
    const int*   src   = (const int*)d_in[1];
    const int*   dst   = (const int*)d_in[2];
    const int*   users = (const int*)d_in[3];
    const int*   pos   = (const int*)d_in[4];
    const int*   neg   = (const int*)d_in[5];
    const int E = in_sizes[1];
    float* out = (float*)d_out;

    unsigned char* hf_a;  hipGetSymbolAddress((void**)&hf_a, HIP_SYMBOL(g_hf8));
    unsigned char* hf_b = hf_a + (size_t)N_NODES * DIM;

    zero_small<<<1024, 256, 0, stream>>>();

    const int STAGE_BLOCKS = (E + 1024 * EDGES_PER_THREAD - 1) / (1024 * EDGES_PER_THREAD);
    stage_buckets<<<STAGE_BLOCKS, 1024, 0, stream>>>(src, dst, E);
    btotals_scan<<<1, 512, 0, stream>>>(E);
    bucket_finalize<<<NBUCKET, 256, 0, stream>>>();
    bucket_place<<<NBUCKET, 256, 0, stream>>>();

    emb_to_fp8<<<2048, 256, 0, stream>>>(emb, hf_a);

    // layer 0 contribution (emb itself, f32)
    gather_acc_f32<<<(3 * BATCH * 64 + 255) / 256, 256, 0, stream>>>(emb, users, pos, neg);

    // layer 1: full pull (needed as input to layer 2)
    pull_layer_fp8<<<(N_NODES * 64 + 255) / 256, 256, 0, stream>>>(hf_a, hf_b);
    gather_acc_fp8<<<(3 * BATCH * 64 + 255) / 256, 256, 0, stream>>>(hf_b, users, pos, neg);

    // layer 2: full pull (needed as input to layer 3's sampled pull)
    pull_layer_fp8<<<(N_NODES * 64 + 255) / 256, 256, 0, stream>>>(hf_b, hf_a);
    gather_acc_fp8<<<(3 * BATCH * 64 + 255) / 256, 256, 0, stream>>>(hf_a, users, pos, neg);

    // layer 3: only the 3*BATCH sampled rows are ever read — pull just those
    pull_sampled<<<(3 * BATCH * 64 + 255) / 256, 256, 0, stream>>>(hf_a, users, pos, neg);

    score_reduce<<<(BATCH * 64 + 255) / 256, 256, 0, stream>>>(emb, users, pos, neg);
    final_reduce<<<1, 256, 0, stream>>>(out);
}

// Round 12
// 225.593 us; speedup vs baseline: 2.3654x; 1.0932x over previous
//
#include <hip/hip_runtime.h>
#include <hip/hip_fp8.h>
#include <math.h>

#define N_NODES 100000
#define DIM 64
#define NUM_LAYER 3
#define BATCH 4096
#define REG_WEIGHT 1e-4f
#define NBUCKET 391                            // dst >> 8 buckets (256 nodes each)
#define STAGE_CAP 4096                         // fixed staging capacity per bucket
#define CURPAD 16                              // ints: 64B pad per bucket cursor
#define H_SCALE 64.0f
#define H_INV_SCALE (1.0f / 64.0f)

// Scratch as device globals (pattern passed R2..R11).
__device__ unsigned char g_hf8[2][(size_t)N_NODES * DIM]; // fp8 ping-pong h (scaled)
__device__ float g_sums[(size_t)3 * BATCH * DIM];  // sampled-row accumulators (f32)
__device__ int   g_row_ptr[N_NODES + 1];           // CSR row offsets (by dst)
__device__ float g_dinv[N_NODES];                  // deg^-0.5
__device__ int   g_bcur[NBUCKET * CURPAD];         // padded bucket staging cursors
__device__ int   g_bbase[NBUCKET];                 // bucket base offsets in CSR
__device__ int2  g_stage[NBUCKET * STAGE_CAP];     // staged (src, dst), fixed-cap regions
__device__ int2  g_csr[1280000];                   // final packed (src, w-bits) per edge
__device__ float g_part_sp[BATCH];                 // per-wave softplus partials
__device__ float g_part_rg[BATCH];                 // per-wave reg partials

__device__ inline float fp8_to_f32(unsigned int v) {
    __hip_fp8_e4m3 t; t.__x = (__hip_fp8_storage_t)(v & 0xFF); return (float)t;
}
__device__ inline unsigned int f32_to_fp8(float f) {
    __hip_fp8_e4m3 t(f); return (unsigned int)t.__x;
}

// ---- init bucket staging cursors (tiny) ----
__global__ void init_bcur() {
    int i = blockIdx.x * blockDim.x + threadIdx.x;
    if (i < NBUCKET) g_bcur[i * CURPAD] = i * STAGE_CAP;
}

// ---- stage pass: LDS histogram per block -> few padded global reservations ->
//      per-block sequential-run stores into fixed-cap bucket staging regions ----
#define EDGES_PER_THREAD 8
__global__ void __launch_bounds__(1024) stage_buckets(const int* __restrict__ src,
                                                      const int* __restrict__ dst, int E) {
    __shared__ int h[NBUCKET];
    __shared__ int cur[NBUCKET];
    int tid = threadIdx.x;
    int base = blockIdx.x * (1024 * EDGES_PER_THREAD);
    for (int i = tid; i < NBUCKET; i += 1024) h[i] = 0;
    __syncthreads();
    int myd[EDGES_PER_THREAD], mys[EDGES_PER_THREAD];
    #pragma unroll
    for (int k = 0; k < EDGES_PER_THREAD; ++k) {
        int e = base + k * 1024 + tid;
        if (e < E) {
            myd[k] = dst[e]; mys[k] = src[e];
            atomicAdd(&h[myd[k] >> 8], 1);
        } else myd[k] = -1;
    }
    __syncthreads();
    for (int i = tid; i < NBUCKET; i += 1024) {
        int c = h[i];
        cur[i] = c ? atomicAdd(&g_bcur[i * CURPAD], c) : 0;  // reserve run in bucket region
    }
    __syncthreads();
    #pragma unroll
    for (int k = 0; k < EDGES_PER_THREAD; ++k) {
        if (myd[k] >= 0) {
            int p = atomicAdd(&cur[myd[k] >> 8], 1);          // LDS cursor -> slot
            g_stage[p] = make_int2(mys[k], myd[k]);
        }
    }
}

// ---- single-block exclusive scan of the 391 bucket totals -> CSR bucket bases ----
__global__ void btotals_scan(int E) {
    __shared__ int sm[512];
    int t = threadIdx.x;
    int c = (t < NBUCKET) ? (g_bcur[t * CURPAD] - t * STAGE_CAP) : 0;
    sm[t] = c;
    __syncthreads();
    for (int off = 1; off < 512; off <<= 1) {
        int x = (t >= off) ? sm[t - off] : 0;
        __syncthreads();
        sm[t] += x;
        __syncthreads();
    }
    if (t < NBUCKET) g_bbase[t] = sm[t] - c;   // exclusive
    if (t == 0) g_row_ptr[N_NODES] = E;
}

// ---- per-bucket: LDS degree hist + scan -> row_ptr & dinv (NO global atomics) ----
__global__ void bucket_finalize() {
    __shared__ int lh[256];
    __shared__ int sc[256];
    int b = blockIdx.x, t = threadIdx.x;
    int cnt  = g_bcur[b * CURPAD] - b * STAGE_CAP;
    int sbeg = b * STAGE_CAP;
    lh[t] = 0;
    __syncthreads();
    for (int k = t; k < cnt; k += 256)
        atomicAdd(&lh[g_stage[sbeg + k].y & 255], 1);
    __syncthreads();
    int v = lh[t];
    sc[t] = v;
    __syncthreads();
    for (int off = 1; off < 256; off <<= 1) {
        int x = (t >= off) ? sc[t - off] : 0;
        __syncthreads();
        sc[t] += x;
        __syncthreads();
    }
    int node = (b << 8) + t;
    if (node < N_NODES) {
        g_row_ptr[node] = g_bbase[b] + sc[t] - v;            // exclusive
        g_dinv[node]    = (v > 0) ? rsqrtf((float)v) : 0.0f;
    }
}

// ---- per-bucket: scatter staged edges into the bucket's 26 KB CSR window ----
__global__ void bucket_place() {
    __shared__ int cur[256];
    int b = blockIdx.x, t = threadIdx.x;
    int cnt  = g_bcur[b * CURPAD] - b * STAGE_CAP;
    int sbeg = b * STAGE_CAP;
    int node = (b << 8) + t;
    cur[t] = (node < N_NODES) ? g_row_ptr[node] : 0;
    __syncthreads();
    for (int k = t; k < cnt; k += 256) {
        int2 sd = g_stage[sbeg + k];
        int pos = atomicAdd(&cur[sd.y & 255], 1);            // LDS cursor, block-local
        float w = g_dinv[sd.x] * g_dinv[sd.y];
        g_csr[pos] = make_int2(sd.x, __float_as_int(w));
    }
}

// ---- convert emb (f32) to scaled fp8 ----
__global__ void emb_to_fp8(const float* __restrict__ emb, unsigned char* __restrict__ hf) {
    size_t i = (size_t)blockIdx.x * blockDim.x + threadIdx.x;
    size_t stride = (size_t)gridDim.x * blockDim.x;
    for (size_t k = i; k < (size_t)N_NODES * DIM; k += stride)
        hf[k] = (unsigned char)f32_to_fp8(emb[k] * H_SCALE);
}

// ---- pull one layer, dword-group form: wave = 4 groups x 16 lanes; each group
//      processes one edge's 64 B row as 16 dword loads (4 edges per load inst,
//      8 in flight per loop iter). CSR lanes >= cnt carry w=0 -> self-masking. ----
__global__ void pull_layer_fp8(const unsigned char* __restrict__ h,
                               unsigned char* __restrict__ hn) {
    int wid  = (blockIdx.x * blockDim.x + threadIdx.x) >> 6;
    int lane = threadIdx.x & 63;
    if (wid >= N_NODES) return;
    int g  = lane >> 4;      // group 0..3 (edge slot)
    int li = lane & 15;      // dword index in row
    int beg = g_row_ptr[wid], end = g_row_ptr[wid + 1];
    float a0 = 0.f, a1 = 0.f, a2 = 0.f, a3 = 0.f;   // dims 4li..4li+3 partial
    for (int base = beg; base < end; base += 64) {
        int k = base + lane;
        int s = 0; float w = 0.0f;
        if (k < end) { int2 ew = g_csr[k]; s = ew.x; w = __int_as_float(ew.y); }
        int cnt = min(64, end - base);
        for (int j = 0; j < cnt; j += 8) {
            int   sA = __shfl(s, j + g);
            float wA = __shfl(w, j + g);
            int   sB = __shfl(s, j + 4 + g);
            float wB = __shfl(w, j + 4 + g);
            unsigned int dA = *(const unsigned int*)(h + (size_t)sA * DIM + li * 4);
            unsigned int dB = *(const unsigned int*)(h + (size_t)sB * DIM + li * 4);
            a0 = fmaf(wA, fp8_to_f32(dA),       a0);
            a1 = fmaf(wA, fp8_to_f32(dA >> 8),  a1);
            a2 = fmaf(wA, fp8_to_f32(dA >> 16), a2);
            a3 = fmaf(wA, fp8_to_f32(dA >> 24), a3);
            a0 = fmaf(wB, fp8_to_f32(dB),       a0);
            a1 = fmaf(wB, fp8_to_f32(dB >> 8),  a1);
            a2 = fmaf(wB, fp8_to_f32(dB >> 16), a2);
            a3 = fmaf(wB, fp8_to_f32(dB >> 24), a3);
        }
    }
    // cross-group butterfly: combine the 4 edge-slot partials per dim
    #pragma unroll
    for (int off = 16; off < 64; off <<= 1) {
        a0 += __shfl_xor(a0, off);
        a1 += __shfl_xor(a1, off);
        a2 += __shfl_xor(a2, off);
        a3 += __shfl_xor(a3, off);
    }
    if (lane < 16) {
        unsigned int outw = f32_to_fp8(a0) | (f32_to_fp8(a1) << 8) |
                            (f32_to_fp8(a2) << 16) | (f32_to_fp8(a3) << 24);
        *(unsigned int*)(hn + (size_t)wid * DIM + li * 4) = outw;
    }
}

// ---- final layer for sampled rows ONLY, fused with the layer-2 sampled gather ----
__global__ void pull_sampled(const unsigned char* __restrict__ h,
                             const int* __restrict__ users, const int* __restrict__ pos,
                             const int* __restrict__ neg) {
    int wid  = (blockIdx.x * blockDim.x + threadIdx.x) >> 6;
    int lane = threadIdx.x & 63;
    if (wid >= 3 * BATCH) return;
    int which = wid / BATCH;
    int i     = wid - which * BATCH;
    const int* idx = (which == 0) ? users : ((which == 1) ? pos : neg);
    int node = idx[i];
    int g  = lane >> 4;
    int li = lane & 15;
    int beg = g_row_ptr[node], end = g_row_ptr[node + 1];
    float a0 = 0.f, a1 = 0.f, a2 = 0.f, a3 = 0.f;
    for (int base = beg; base < end; base += 64) {
        int k = base + lane;
        int s = 0; float w = 0.0f;
        if (k < end) { int2 ew = g_csr[k]; s = ew.x; w = __int_as_float(ew.y); }
        int cnt = min(64, end - base);
        for (int j = 0; j < cnt; j += 8) {
            int   sA = __shfl(s, j + g);
            float wA = __shfl(w, j + g);
            int   sB = __shfl(s, j + 4 + g);
            float wB = __shfl(w, j + 4 + g);
            unsigned int dA = *(const unsigned int*)(h + (size_t)sA * DIM + li * 4);
            unsigned int dB = *(const unsigned int*)(h + (size_t)sB * DIM + li * 4);
            a0 = fmaf(wA, fp8_to_f32(dA),       a0);
            a1 = fmaf(wA, fp8_to_f32(dA >> 8),  a1);
            a2 = fmaf(wA, fp8_to_f32(dA >> 16), a2);
            a3 = fmaf(wA, fp8_to_f32(dA >> 24), a3);
            a0 = fmaf(wB, fp8_to_f32(dB),       a0);
            a1 = fmaf(wB, fp8_to_f32(dB >> 8),  a1);
            a2 = fmaf(wB, fp8_to_f32(dB >> 16), a2);
            a3 = fmaf(wB, fp8_to_f32(dB >> 24), a3);
        }
    }
    #pragma unroll
    for (int off = 16; off < 64; off <<= 1) {
        a0 += __shfl_xor(a0, off);
        a1 += __shfl_xor(a1, off);
        a2 += __shfl_xor(a2, off);
        a3 += __shfl_xor(a3, off);
    }
    if (lane < 16) {
        // fused: + layer-2 value of this node (the old gather_acc_fp8 for hf after layer 2)
        unsigned int dn = *(const unsigned int*)(h + (size_t)node * DIM + li * 4);
        float* sp = &g_sums[(size_t)wid * DIM + li * 4];
        sp[0] += (a0 + fp8_to_f32(dn))       * H_INV_SCALE;
        sp[1] += (a1 + fp8_to_f32(dn >> 8))  * H_INV_SCALE;
        sp[2] += (a2 + fp8_to_f32(dn >> 16)) * H_INV_SCALE;
        sp[3] += (a3 + fp8_to_f32(dn >> 24)) * H_INV_SCALE;
    }
}

// ---- layer-0 sampled gather: ASSIGNS g_sums (first writer; kills the 3MB zero pass) ----
__global__ void gather_acc_f32(const float* __restrict__ h,
                               const int* __restrict__ users, const int* __restrict__ pos,
                               const int* __restrict__ neg) {
    int wid  = (blockIdx.x * blockDim.x + threadIdx.x) >> 6;
    int lane = threadIdx.x & 63;
    if (wid >= 3 * BATCH) return;
    int which = wid / BATCH;
    int i     = wid - which * BATCH;
    const int* idx = (which == 0) ? users : ((which == 1) ? pos : neg);
    int node = idx[i];
    g_sums[(size_t)wid * DIM + lane] = h[(size_t)node * DIM + lane];
}

// ---- layer-1 sampled gather (fp8 scaled source) ----
__global__ void gather_acc_fp8(const unsigned char* __restrict__ h,
                               const int* __restrict__ users, const int* __restrict__ pos,
                               const int* __restrict__ neg) {
    int wid  = (blockIdx.x * blockDim.x + threadIdx.x) >> 6;
    int lane = threadIdx.x & 63;
    if (wid >= 3 * BATCH) return;
    int which = wid / BATCH;
    int i     = wid - which * BATCH;
    const int* idx = (which == 0) ? users : ((which == 1) ? pos : neg);
    int node = idx[i];
    g_sums[(size_t)wid * DIM + lane] += fp8_to_f32(h[(size_t)node * DIM + lane]) * H_INV_SCALE;
}

// ---- per-sample scores + reg partials, wave-64 reduce, partials to arrays (NO atomics) ----
__global__ void score_reduce(const float* __restrict__ emb,
                             const int* __restrict__ users, const int* __restrict__ pos,
                             const int* __restrict__ neg) {
    int wid  = (blockIdx.x * blockDim.x + threadIdx.x) >> 6;
    int lane = threadIdx.x & 63;
    if (wid >= BATCH) return;
    float u = 0.25f * g_sums[(size_t)wid * DIM + lane];
    float p = 0.25f * g_sums[(size_t)(BATCH + wid) * DIM + lane];
    float n = 0.25f * g_sums[(size_t)(2 * BATCH + wid) * DIM + lane];
    float ps = u * p;
    float ns = u * n;
    float u0 = emb[(size_t)users[wid] * DIM + lane];
    float p0 = emb[(size_t)pos[wid]   * DIM + lane];
    float n0 = emb[(size_t)neg[wid]   * DIM + lane];
    float rg = u0 * u0 + p0 * p0 + n0 * n0;
    #pragma unroll
    for (int off = 32; off > 0; off >>= 1) {
        ps += __shfl_down(ps, off);
        ns += __shfl_down(ns, off);
        rg += __shfl_down(rg, off);
    }
    if (lane == 0) {
        float x  = ns - ps;
        float sp = fmaxf(x, 0.0f) + log1pf(expf(-fabsf(x)));  // stable softplus
        g_part_sp[wid] = sp;
        g_part_rg[wid] = rg;
    }
}

// ---- single-block final reduction over the 4096 per-wave partials ----
__global__ void final_reduce(float* __restrict__ out) {
    __shared__ float s_sp[256], s_rg[256];
    int t = threadIdx.x;
    float sp = 0.0f, rg = 0.0f;
    for (int i = t; i < BATCH; i += 256) { sp += g_part_sp[i]; rg += g_part_rg[i]; }
    s_sp[t] = sp; s_rg[t] = rg;
    __syncthreads();
    for (int off = 128; off > 0; off >>= 1) {
        if (t < off) { s_sp[t] += s_sp[t + off]; s_rg[t] += s_rg[t + off]; }
        __syncthreads();
    }
    if (t == 0) {
        float loss_emb = s_sp[0] / (float)BATCH;
        float reg      = 0.5f * s_rg[0] / (float)BATCH * REG_WEIGHT;
        out[0] = loss_emb + reg;
        out[1] = loss_emb;
        out[2] = reg;
    }
}

extern "C" void kernel_launch(void* const* d_in, const int* in_sizes, int n_in,
                              void* d_out, int out_size, void* d_ws, size_t ws_size,
                              hipStream_t stream) {
    const float* emb   = (const float*)d_in[0];
    const int*   src   = (const int*)d_in[1];
    const int*   dst   = (const int*)d_in[2];
    const int*   users = (const int*)d_in[3];
    const int*   pos   = (const int*)d_in[4];
    const int*   neg   = (const int*)d_in[5];
    const int E = in_sizes[1];
    float* out = (float*)d_out;

    unsigned char* hf_a;  hipGetSymbolAddress((void**)&hf_a, HIP_SYMBOL(g_hf8));
    unsigned char* hf_b = hf_a + (size_t)N_NODES * DIM;

    init_bcur<<<(NBUCKET + 255) / 256, 256, 0, stream>>>();

    const int STAGE_BLOCKS = (E + 1024 * EDGES_PER_THREAD - 1) / (1024 * EDGES_PER_THREAD);
    stage_buckets<<<STAGE_BLOCKS, 1024, 0, stream>>>(src, dst, E);
    btotals_scan<<<1, 512, 0, stream>>>(E);
    bucket_finalize<<<NBUCKET, 256, 0, stream>>>();
    bucket_place<<<NBUCKET, 256, 0, stream>>>();

    emb_to_fp8<<<2048, 256, 0, stream>>>(emb, hf_a);

    // layer 0 contribution (emb itself, f32) — assigns g_sums
    gather_acc_f32<<<(3 * BATCH * 64 + 255) / 256, 256, 0, stream>>>(emb, users, pos, neg);

    // layer 1: full pull (needed as input to layer 2)
    pull_layer_fp8<<<(N_NODES * 64 + 255) / 256, 256, 0, stream>>>(hf_a, hf_b);
    gather_acc_fp8<<<(3 * BATCH * 64 + 255) / 256, 256, 0, stream>>>(hf_b, users, pos, neg);

    // layer 2: full pull (needed as input to layer 3's sampled pull)
    pull_layer_fp8<<<(N_NODES * 64 + 255) / 256, 256, 0, stream>>>(hf_b, hf_a);

    // layer 3 sampled pull + fused layer-2 sampled gather
    pull_sampled<<<(3 * BATCH * 64 + 255) / 256, 256, 0, stream>>>(hf_a, users, pos, neg);

    score_reduce<<<(BATCH * 64 + 255) / 256, 256, 0, stream>>>(emb, users, pos, neg);
    final_reduce<<<1, 256, 0, stream>>>(out);
}

// Round 13
// 211.242 us; speedup vs baseline: 2.5261x; 1.0679x over previous
//
#include <hip/hip_runtime.h>
#include <hip/hip_fp8.h>
#include <math.h>

#define N_NODES 100000
#define DIM 64
#define NUM_LAYER 3
#define BATCH 4096
#define REG_WEIGHT 1e-4f
#define NBUCKET 391                            // dst >> 8 buckets (256 nodes each)
#define STAGE_CAP 4096                         // fixed staging capacity per bucket (14 sigma)
#define CURPAD 16                              // ints: 64B pad per bucket cursor
#define H_SCALE 64.0f
#define H_INV_SCALE (1.0f / 64.0f)

// Scratch as device globals (pattern passed R2..R12).
__device__ unsigned char g_hf8[2][(size_t)N_NODES * DIM]; // fp8 ping-pong h (scaled)
__device__ float g_sums[(size_t)3 * BATCH * DIM];  // sampled-row accumulators (f32)
__device__ int   g_row_ptr[N_NODES + 1];           // CSR row offsets (by dst)
__device__ float g_dinv[N_NODES];                  // deg^-0.5
__device__ int   g_bcur[NBUCKET * CURPAD];         // padded bucket staging cursors
__device__ unsigned int g_stage[NBUCKET * STAGE_CAP]; // packed (src<<8)|(dst&255), 4B/edge
__device__ int2  g_csr[1280000];                   // final packed (src, w-bits) per edge
__device__ float g_part_sp[BATCH];                 // per-wave softplus partials
__device__ float g_part_rg[BATCH];                 // per-wave reg partials

__device__ inline float fp8_to_f32(unsigned int v) {
    __hip_fp8_e4m3 t; t.__x = (__hip_fp8_storage_t)(v & 0xFF); return (float)t;
}
__device__ inline unsigned int f32_to_fp8(float f) {
    __hip_fp8_e4m3 t(f); return (unsigned int)t.__x;
}

// ---- fused prelude: bcur init + emb->fp8 (dword stores) + layer-0 sampled gather ----
__global__ void prelude(const float* __restrict__ emb,
                        const int* __restrict__ users, const int* __restrict__ pos,
                        const int* __restrict__ neg) {
    int i = blockIdx.x * blockDim.x + threadIdx.x;
    int stride = gridDim.x * blockDim.x;
    for (int k = i; k < NBUCKET; k += stride) g_bcur[k * CURPAD] = k * STAGE_CAP;
    const int NW = N_NODES * DIM / 4;
    unsigned int* hw = (unsigned int*)g_hf8[0];
    for (int k = i; k < NW; k += stride) {
        const float* e = emb + (size_t)k * 4;
        hw[k] = f32_to_fp8(e[0] * H_SCALE)         | (f32_to_fp8(e[1] * H_SCALE) << 8) |
                (f32_to_fp8(e[2] * H_SCALE) << 16) | (f32_to_fp8(e[3] * H_SCALE) << 24);
    }
    for (int k = i; k < 3 * BATCH * DIM; k += stride) {
        int wid = k >> 6, lane = k & 63;
        int which = wid / BATCH, s = wid - which * BATCH;
        const int* idx = (which == 0) ? users : ((which == 1) ? pos : neg);
        g_sums[k] = emb[(size_t)idx[s] * DIM + lane];   // assign: first writer
    }
}

// ---- stage pass: LDS histogram per block -> few padded global reservations ->
//      per-block sequential-run 4B stores into fixed-cap bucket staging regions ----
#define EDGES_PER_THREAD 8
__global__ void __launch_bounds__(1024) stage_buckets(const int* __restrict__ src,
                                                      const int* __restrict__ dst, int E) {
    __shared__ int h[NBUCKET];
    __shared__ int cur[NBUCKET];
    int tid = threadIdx.x;
    int base = blockIdx.x * (1024 * EDGES_PER_THREAD);
    for (int i = tid; i < NBUCKET; i += 1024) h[i] = 0;
    __syncthreads();
    int myd[EDGES_PER_THREAD], mys[EDGES_PER_THREAD];
    #pragma unroll
    for (int k = 0; k < EDGES_PER_THREAD; ++k) {
        int e = base + k * 1024 + tid;
        if (e < E) {
            myd[k] = dst[e]; mys[k] = src[e];
            atomicAdd(&h[myd[k] >> 8], 1);
        } else myd[k] = -1;
    }
    __syncthreads();
    for (int i = tid; i < NBUCKET; i += 1024) {
        int c = h[i];
        cur[i] = c ? atomicAdd(&g_bcur[i * CURPAD], c) : 0;  // reserve run in bucket region
    }
    __syncthreads();
    #pragma unroll
    for (int k = 0; k < EDGES_PER_THREAD; ++k) {
        if (myd[k] >= 0) {
            int p = atomicAdd(&cur[myd[k] >> 8], 1);          // LDS cursor -> slot
            g_stage[p] = (unsigned int)((mys[k] << 8) | (myd[k] & 255));
        }
    }
}

// ---- per-bucket: inline 391-scan for bucket base + LDS degree hist + scan ->
//      row_ptr & dinv (NO global atomics, no separate btotals kernel) ----
__global__ void __launch_bounds__(512) bucket_finalize() {
    __shared__ int cs[512];
    __shared__ int lh[256], sc[256];
    int b = blockIdx.x, t = threadIdx.x;
    int c = (t < NBUCKET) ? (g_bcur[t * CURPAD] - t * STAGE_CAP) : 0;
    cs[t] = c;
    __syncthreads();
    for (int off = 1; off < 512; off <<= 1) {
        int x = (t >= off) ? cs[t - off] : 0;
        __syncthreads();
        cs[t] += x;
        __syncthreads();
    }
    int mybase = (b > 0) ? cs[b - 1] : 0;         // exclusive prefix at bucket b
    int cnt    = cs[b] - mybase;
    if (b == 0 && t == 0) g_row_ptr[N_NODES] = cs[NBUCKET - 1];
    int sbeg = b * STAGE_CAP;
    if (t < 256) lh[t] = 0;
    __syncthreads();
    for (int k = t; k < cnt; k += 512)
        atomicAdd(&lh[g_stage[sbeg + k] & 255], 1);
    __syncthreads();
    int v = 0;
    if (t < 256) { v = lh[t]; sc[t] = v; }
    __syncthreads();
    for (int off = 1; off < 256; off <<= 1) {
        int x = (t >= off && t < 256) ? sc[t - off] : 0;
        __syncthreads();
        if (t < 256) sc[t] += x;
        __syncthreads();
    }
    if (t < 256) {
        int node = (b << 8) + t;
        if (node < N_NODES) {
            g_row_ptr[node] = mybase + sc[t] - v;            // exclusive
            g_dinv[node]    = (v > 0) ? rsqrtf((float)v) : 0.0f;
        }
    }
}

// ---- per-bucket: scatter staged edges into the bucket's 26 KB CSR window ----
__global__ void bucket_place() {
    __shared__ int cur[256];
    int b = blockIdx.x, t = threadIdx.x;
    int cnt  = g_bcur[b * CURPAD] - b * STAGE_CAP;
    int sbeg = b * STAGE_CAP;
    int node = (b << 8) + t;
    cur[t] = (node < N_NODES) ? g_row_ptr[node] : 0;
    __syncthreads();
    for (int k = t; k < cnt; k += 256) {
        unsigned int e = g_stage[sbeg + k];
        int dl = e & 255;
        int s  = (int)(e >> 8);
        int pos = atomicAdd(&cur[dl], 1);                    // LDS cursor, block-local
        int d = (b << 8) + dl;
        float w = g_dinv[s] * g_dinv[d];
        g_csr[pos] = make_int2(s, __float_as_int(w));
    }
}

// ---- pull one layer, dword-group form (unchanged from R12) ----
__global__ void pull_layer_fp8(const unsigned char* __restrict__ h,
                               unsigned char* __restrict__ hn) {
    int wid  = (blockIdx.x * blockDim.x + threadIdx.x) >> 6;
    int lane = threadIdx.x & 63;
    if (wid >= N_NODES) return;
    int g  = lane >> 4;      // group 0..3 (edge slot)
    int li = lane & 15;      // dword index in row
    int beg = g_row_ptr[wid], end = g_row_ptr[wid + 1];
    float a0 = 0.f, a1 = 0.f, a2 = 0.f, a3 = 0.f;
    for (int base = beg; base < end; base += 64) {
        int k = base + lane;
        int s = 0; float w = 0.0f;
        if (k < end) { int2 ew = g_csr[k]; s = ew.x; w = __int_as_float(ew.y); }
        int cnt = min(64, end - base);
        for (int j = 0; j < cnt; j += 8) {
            int   sA = __shfl(s, j + g);
            float wA = __shfl(w, j + g);
            int   sB = __shfl(s, j + 4 + g);
            float wB = __shfl(w, j + 4 + g);
            unsigned int dA = *(const unsigned int*)(h + (size_t)sA * DIM + li * 4);
            unsigned int dB = *(const unsigned int*)(h + (size_t)sB * DIM + li * 4);
            a0 = fmaf(wA, fp8_to_f32(dA),       a0);
            a1 = fmaf(wA, fp8_to_f32(dA >> 8),  a1);
            a2 = fmaf(wA, fp8_to_f32(dA >> 16), a2);
            a3 = fmaf(wA, fp8_to_f32(dA >> 24), a3);
            a0 = fmaf(wB, fp8_to_f32(dB),       a0);
            a1 = fmaf(wB, fp8_to_f32(dB >> 8),  a1);
            a2 = fmaf(wB, fp8_to_f32(dB >> 16), a2);
            a3 = fmaf(wB, fp8_to_f32(dB >> 24), a3);
        }
    }
    #pragma unroll
    for (int off = 16; off < 64; off <<= 1) {
        a0 += __shfl_xor(a0, off);
        a1 += __shfl_xor(a1, off);
        a2 += __shfl_xor(a2, off);
        a3 += __shfl_xor(a3, off);
    }
    if (lane < 16) {
        unsigned int outw = f32_to_fp8(a0) | (f32_to_fp8(a1) << 8) |
                            (f32_to_fp8(a2) << 16) | (f32_to_fp8(a3) << 24);
        *(unsigned int*)(hn + (size_t)wid * DIM + li * 4) = outw;
    }
}

// ---- final layer for sampled rows ONLY, fused with the layer-2 sampled gather ----
__global__ void pull_sampled(const unsigned char* __restrict__ h,
                             const int* __restrict__ users, const int* __restrict__ pos,
                             const int* __restrict__ neg) {
    int wid  = (blockIdx.x * blockDim.x + threadIdx.x) >> 6;
    int lane = threadIdx.x & 63;
    if (wid >= 3 * BATCH) return;
    int which = wid / BATCH;
    int i     = wid - which * BATCH;
    const int* idx = (which == 0) ? users : ((which == 1) ? pos : neg);
    int node = idx[i];
    int g  = lane >> 4;
    int li = lane & 15;
    int beg = g_row_ptr[node], end = g_row_ptr[node + 1];
    float a0 = 0.f, a1 = 0.f, a2 = 0.f, a3 = 0.f;
    for (int base = beg; base < end; base += 64) {
        int k = base + lane;
        int s = 0; float w = 0.0f;
        if (k < end) { int2 ew = g_csr[k]; s = ew.x; w = __int_as_float(ew.y); }
        int cnt = min(64, end - base);
        for (int j = 0; j < cnt; j += 8) {
            int   sA = __shfl(s, j + g);
            float wA = __shfl(w, j + g);
            int   sB = __shfl(s, j + 4 + g);
            float wB = __shfl(w, j + 4 + g);
            unsigned int dA = *(const unsigned int*)(h + (size_t)sA * DIM + li * 4);
            unsigned int dB = *(const unsigned int*)(h + (size_t)sB * DIM + li * 4);
            a0 = fmaf(wA, fp8_to_f32(dA),       a0);
            a1 = fmaf(wA, fp8_to_f32(dA >> 8),  a1);
            a2 = fmaf(wA, fp8_to_f32(dA >> 16), a2);
            a3 = fmaf(wA, fp8_to_f32(dA >> 24), a3);
            a0 = fmaf(wB, fp8_to_f32(dB),       a0);
            a1 = fmaf(wB, fp8_to_f32(dB >> 8),  a1);
            a2 = fmaf(wB, fp8_to_f32(dB >> 16), a2);
            a3 = fmaf(wB, fp8_to_f32(dB >> 24), a3);
        }
    }
    #pragma unroll
    for (int off = 16; off < 64; off <<= 1) {
        a0 += __shfl_xor(a0, off);
        a1 += __shfl_xor(a1, off);
        a2 += __shfl_xor(a2, off);
        a3 += __shfl_xor(a3, off);
    }
    if (lane < 16) {
        unsigned int dn = *(const unsigned int*)(h + (size_t)node * DIM + li * 4);
        float* sp = &g_sums[(size_t)wid * DIM + li * 4];
        sp[0] += (a0 + fp8_to_f32(dn))       * H_INV_SCALE;
        sp[1] += (a1 + fp8_to_f32(dn >> 8))  * H_INV_SCALE;
        sp[2] += (a2 + fp8_to_f32(dn >> 16)) * H_INV_SCALE;
        sp[3] += (a3 + fp8_to_f32(dn >> 24)) * H_INV_SCALE;
    }
}

// ---- layer-1 sampled gather (fp8 scaled source) ----
__global__ void gather_acc_fp8(const unsigned char* __restrict__ h,
                               const int* __restrict__ users, const int* __restrict__ pos,
                               const int* __restrict__ neg) {
    int wid  = (blockIdx.x * blockDim.x + threadIdx.x) >> 6;
    int lane = threadIdx.x & 63;
    if (wid >= 3 * BATCH) return;
    int which = wid / BATCH;
    int i     = wid - which * BATCH;
    const int* idx = (which == 0) ? users : ((which == 1) ? pos : neg);
    int node = idx[i];
    g_sums[(size_t)wid * DIM + lane] += fp8_to_f32(h[(size_t)node * DIM + lane]) * H_INV_SCALE;
}

// ---- per-sample scores + reg partials, wave-64 reduce, partials to arrays (NO atomics) ----
__global__ void score_reduce(const float* __restrict__ emb,
                             const int* __restrict__ users, const int* __restrict__ pos,
                             const int* __restrict__ neg) {
    int wid  = (blockIdx.x * blockDim.x + threadIdx.x) >> 6;
    int lane = threadIdx.x & 63;
    if (wid >= BATCH) return;
    float u = 0.25f * g_sums[(size_t)wid * DIM + lane];
    float p = 0.25f * g_sums[(size_t)(BATCH + wid) * DIM + lane];
    float n = 0.25f * g_sums[(size_t)(2 * BATCH + wid) * DIM + lane];
    float ps = u * p;
    float ns = u * n;
    float u0 = emb[(size_t)users[wid] * DIM + lane];
    float p0 = emb[(size_t)pos[wid]   * DIM + lane];
    float n0 = emb[(size_t)neg[wid]   * DIM + lane];
    float rg = u0 * u0 + p0 * p0 + n0 * n0;
    #pragma unroll
    for (int off = 32; off > 0; off >>= 1) {
        ps += __shfl_down(ps, off);
        ns += __shfl_down(ns, off);
        rg += __shfl_down(rg, off);
    }
    if (lane == 0) {
        float x  = ns - ps;
        float sp = fmaxf(x, 0.0f) + log1pf(expf(-fabsf(x)));  // stable softplus
        g_part_sp[wid] = sp;
        g_part_rg[wid] = rg;
    }
}

// ---- single-block final reduction over the 4096 per-wave partials ----
__global__ void final_reduce(float* __restrict__ out) {
    __shared__ float s_sp[256], s_rg[256];
    int t = threadIdx.x;
    float sp = 0.0f, rg = 0.0f;
    for (int i = t; i < BATCH; i += 256) { sp += g_part_sp[i]; rg += g_part_rg[i]; }
    s_sp[t] = sp; s_rg[t] = rg;
    __syncthreads();
    for (int off = 128; off > 0; off >>= 1) {
        if (t < off) { s_sp[t] += s_sp[t + off]; s_rg[t] += s_rg[t + off]; }
        __syncthreads();
    }
    if (t == 0) {
        float loss_emb = s_sp[0] / (float)BATCH;
        float reg      = 0.5f * s_rg[0] / (float)BATCH * REG_WEIGHT;
        out[0] = loss_emb + reg;
        out[1] = loss_emb;
        out[2] = reg;
    }
}

extern "C" void kernel_launch(void* const* d_in, const int* in_sizes, int n_in,
                              void* d_out, int out_size, void* d_ws, size_t ws_size,
                              hipStream_t stream) {
    const float* emb   = (const float*)d_in[0];
    const int*   src   = (const int*)d_in[1];
    const int*   dst   = (const int*)d_in[2];
    const int*   users = (const int*)d_in[3];
    const int*   pos   = (const int*)d_in[4];
    const int*   neg   = (const int*)d_in[5];
    const int E = in_sizes[1];
    float* out = (float*)d_out;

    unsigned char* hf_a;  hipGetSymbolAddress((void**)&hf_a, HIP_SYMBOL(g_hf8));
    unsigned char* hf_b = hf_a + (size_t)N_NODES * DIM;

    prelude<<<1024, 256, 0, stream>>>(emb, users, pos, neg);

    const int STAGE_BLOCKS = (E + 1024 * EDGES_PER_THREAD - 1) / (1024 * EDGES_PER_THREAD);
    stage_buckets<<<STAGE_BLOCKS, 1024, 0, stream>>>(src, dst, E);
    bucket_finalize<<<NBUCKET, 512, 0, stream>>>();
    bucket_place<<<NBUCKET, 256, 0, stream>>>();

    // layer 1: full pull (needed as input to layer 2)
    pull_layer_fp8<<<(N_NODES * 64 + 255) / 256, 256, 0, stream>>>(hf_a, hf_b);
    gather_acc_fp8<<<(3 * BATCH * 64 + 255) / 256, 256, 0, stream>>>(hf_b, users, pos, neg);

    // layer 2: full pull (needed as input to layer 3's sampled pull)
    pull_layer_fp8<<<(N_NODES * 64 + 255) / 256, 256, 0, stream>>>(hf_b, hf_a);

    // layer 3 sampled pull + fused layer-2 sampled gather
    pull_sampled<<<(3 * BATCH * 64 + 255) / 256, 256, 0, stream>>>(hf_a, users, pos, neg);

    score_reduce<<<(BATCH * 64 + 255) / 256, 256, 0, stream>>>(emb, users, pos, neg);
    final_reduce<<<1, 256, 0, stream>>>(out);
}

// Round 14
// 209.634 us; speedup vs baseline: 2.5455x; 1.0077x over previous
//
#include <hip/hip_runtime.h>
#include <hip/hip_fp8.h>
#include <math.h>

#define N_NODES 100000
#define DIM 64
#define NUM_LAYER 3
#define BATCH 4096
#define REG_WEIGHT 1e-4f
#define NBUCKET 391                            // dst >> 8 buckets (256 nodes each)
#define STAGE_CAP 4096                         // fixed staging capacity per bucket (14 sigma)
#define CURPAD 16                              // ints: 64B pad per bucket cursor
#define H_SCALE 64.0f
#define H_INV_SCALE (1.0f / 64.0f)

// Scratch as device globals (pattern passed R2..R13).
__device__ unsigned char g_hf8[2][(size_t)N_NODES * DIM]; // fp8 ping-pong h (scaled)
__device__ float g_sums[(size_t)3 * BATCH * DIM];  // sampled-row accumulators (f32)
__device__ int   g_row_ptr[N_NODES + 1];           // CSR row offsets (by dst)
__device__ float g_dinv[N_NODES];                  // deg^-0.5 (400 KB, L2-resident)
__device__ int   g_bcur[NBUCKET * CURPAD];         // padded bucket staging cursors
__device__ unsigned int g_stage[NBUCKET * STAGE_CAP]; // packed (src<<8)|(dst&255), 4B/edge
__device__ int   g_csr[1280000];                   // final CSR: src only, 4B/edge
__device__ int   g_shead[N_NODES];                 // node -> first sample idx (or -1)
__device__ int   g_snext[3 * BATCH];               // sample chain links
__device__ float g_part_sp[BATCH];                 // per-wave softplus partials
__device__ float g_part_rg[BATCH];                 // per-wave reg partials

__device__ inline float fp8_to_f32(unsigned int v) {
    __hip_fp8_e4m3 t; t.__x = (__hip_fp8_storage_t)(v & 0xFF); return (float)t;
}
__device__ inline unsigned int f32_to_fp8(float f) {
    __hip_fp8_e4m3 t(f); return (unsigned int)t.__x;
}

// ---- fused prelude: bcur init + shead init + emb->fp8 (dword stores) ----
__global__ void prelude(const float* __restrict__ emb) {
    int i = blockIdx.x * blockDim.x + threadIdx.x;
    int stride = gridDim.x * blockDim.x;
    for (int k = i; k < NBUCKET; k += stride) g_bcur[k * CURPAD] = k * STAGE_CAP;
    for (int k = i; k < N_NODES; k += stride) g_shead[k] = -1;
    const int NW = N_NODES * DIM / 4;
    unsigned int* hw = (unsigned int*)g_hf8[0];
    for (int k = i; k < NW; k += stride) {
        const float* e = emb + (size_t)k * 4;
        hw[k] = f32_to_fp8(e[0] * H_SCALE)         | (f32_to_fp8(e[1] * H_SCALE) << 8) |
                (f32_to_fp8(e[2] * H_SCALE) << 16) | (f32_to_fp8(e[3] * H_SCALE) << 24);
    }
}

// ---- stage pass: LDS histogram -> padded global reservations -> sequential-run
//      4B stores. Also builds the sample chain map (needs prelude's shead=-1). ----
#define EDGES_PER_THREAD 8
__global__ void __launch_bounds__(1024) stage_buckets(const int* __restrict__ src,
                                                      const int* __restrict__ dst, int E,
                                                      const int* __restrict__ users,
                                                      const int* __restrict__ pos,
                                                      const int* __restrict__ neg) {
    __shared__ int h[NBUCKET];
    __shared__ int cur[NBUCKET];
    int tid = threadIdx.x;
    int gt = blockIdx.x * 1024 + tid;
    if (gt < 3 * BATCH) {                       // build sample chains (12288 items)
        int which = gt / BATCH, s = gt - which * BATCH;
        const int* idx = (which == 0) ? users : ((which == 1) ? pos : neg);
        g_snext[gt] = atomicExch(&g_shead[idx[s]], gt);
    }
    int base = blockIdx.x * (1024 * EDGES_PER_THREAD);
    for (int i = tid; i < NBUCKET; i += 1024) h[i] = 0;
    __syncthreads();
    int myd[EDGES_PER_THREAD], mys[EDGES_PER_THREAD];
    #pragma unroll
    for (int k = 0; k < EDGES_PER_THREAD; ++k) {
        int e = base + k * 1024 + tid;
        if (e < E) {
            myd[k] = dst[e]; mys[k] = src[e];
            atomicAdd(&h[myd[k] >> 8], 1);
        } else myd[k] = -1;
    }
    __syncthreads();
    for (int i = tid; i < NBUCKET; i += 1024) {
        int c = h[i];
        cur[i] = c ? atomicAdd(&g_bcur[i * CURPAD], c) : 0;  // reserve run in bucket region
    }
    __syncthreads();
    #pragma unroll
    for (int k = 0; k < EDGES_PER_THREAD; ++k) {
        if (myd[k] >= 0) {
            int p = atomicAdd(&cur[myd[k] >> 8], 1);          // LDS cursor -> slot
            g_stage[p] = (unsigned int)((mys[k] << 8) | (myd[k] & 255));
        }
    }
}

// ---- fused per-bucket: 391-scan for base + degree hist + scan -> row_ptr/dinv,
//      then scatter into the bucket's CSR window (src only, 4B). NO global atomics. ----
__global__ void __launch_bounds__(512) finalize_place() {
    __shared__ int cs[512];
    __shared__ int lh[256], sc[256], cur[256];
    int b = blockIdx.x, t = threadIdx.x;
    int c = (t < NBUCKET) ? (g_bcur[t * CURPAD] - t * STAGE_CAP) : 0;
    cs[t] = c;
    __syncthreads();
    for (int off = 1; off < 512; off <<= 1) {
        int x = (t >= off) ? cs[t - off] : 0;
        __syncthreads();
        cs[t] += x;
        __syncthreads();
    }
    int mybase = (b > 0) ? cs[b - 1] : 0;         // exclusive prefix at bucket b
    int cnt    = cs[b] - mybase;
    if (b == 0 && t == 0) g_row_ptr[N_NODES] = cs[NBUCKET - 1];
    int sbeg = b * STAGE_CAP;
    if (t < 256) lh[t] = 0;
    __syncthreads();
    for (int k = t; k < cnt; k += 512)
        atomicAdd(&lh[g_stage[sbeg + k] & 255], 1);
    __syncthreads();
    int v = 0;
    if (t < 256) { v = lh[t]; sc[t] = v; }
    __syncthreads();
    for (int off = 1; off < 256; off <<= 1) {
        int x = (t >= off && t < 256) ? sc[t - off] : 0;
        __syncthreads();
        if (t < 256) sc[t] += x;
        __syncthreads();
    }
    if (t < 256) {
        int start = mybase + sc[t] - v;
        cur[t] = start;
        int node = (b << 8) + t;
        if (node < N_NODES) {
            g_row_ptr[node] = start;                          // exclusive
            g_dinv[node]    = (v > 0) ? rsqrtf((float)v) : 0.0f;
        }
    }
    __syncthreads();
    for (int k = t; k < cnt; k += 512) {                      // staged chunk is L2-hot
        unsigned int e = g_stage[sbeg + k];
        int pos = atomicAdd(&cur[e & 255], 1);
        g_csr[pos] = (int)(e >> 8);                           // src only
    }
}

// ---- pull one layer, dword-group form; w computed on the fly from L2-resident dinv.
//      do_gather: walk the sample chain and ASSIGN g_sums (layer-1 only). ----
__global__ void pull_layer_fp8(const unsigned char* __restrict__ h,
                               unsigned char* __restrict__ hn, int do_gather) {
    int wid  = (blockIdx.x * blockDim.x + threadIdx.x) >> 6;
    int lane = threadIdx.x & 63;
    if (wid >= N_NODES) return;
    int g  = lane >> 4;      // group 0..3 (edge slot)
    int li = lane & 15;      // dword index in row
    int beg = g_row_ptr[wid], end = g_row_ptr[wid + 1];
    float dinv_d = g_dinv[wid];
    float a0 = 0.f, a1 = 0.f, a2 = 0.f, a3 = 0.f;
    for (int base = beg; base < end; base += 64) {
        int k = base + lane;
        int s = 0; float w = 0.0f;
        if (k < end) { s = g_csr[k]; w = g_dinv[s] * dinv_d; }
        int cnt = min(64, end - base);
        for (int j = 0; j < cnt; j += 8) {
            int   sA = __shfl(s, j + g);
            float wA = __shfl(w, j + g);
            int   sB = __shfl(s, j + 4 + g);
            float wB = __shfl(w, j + 4 + g);
            unsigned int dA = *(const unsigned int*)(h + (size_t)sA * DIM + li * 4);
            unsigned int dB = *(const unsigned int*)(h + (size_t)sB * DIM + li * 4);
            a0 = fmaf(wA, fp8_to_f32(dA),       a0);
            a1 = fmaf(wA, fp8_to_f32(dA >> 8),  a1);
            a2 = fmaf(wA, fp8_to_f32(dA >> 16), a2);
            a3 = fmaf(wA, fp8_to_f32(dA >> 24), a3);
            a0 = fmaf(wB, fp8_to_f32(dB),       a0);
            a1 = fmaf(wB, fp8_to_f32(dB >> 8),  a1);
            a2 = fmaf(wB, fp8_to_f32(dB >> 16), a2);
            a3 = fmaf(wB, fp8_to_f32(dB >> 24), a3);
        }
    }
    #pragma unroll
    for (int off = 16; off < 64; off <<= 1) {
        a0 += __shfl_xor(a0, off);
        a1 += __shfl_xor(a1, off);
        a2 += __shfl_xor(a2, off);
        a3 += __shfl_xor(a3, off);
    }
    if (lane < 16) {
        unsigned int outw = f32_to_fp8(a0) | (f32_to_fp8(a1) << 8) |
                            (f32_to_fp8(a2) << 16) | (f32_to_fp8(a3) << 24);
        *(unsigned int*)(hn + (size_t)wid * DIM + li * 4) = outw;
    }
    if (do_gather) {
        int sidx = g_shead[wid];                 // wave-uniform chain walk
        while (sidx >= 0) {
            if (lane < 16) {
                float* sp = &g_sums[(size_t)sidx * DIM + li * 4];
                sp[0] = a0 * H_INV_SCALE;        // ASSIGN: first writer of g_sums
                sp[1] = a1 * H_INV_SCALE;
                sp[2] = a2 * H_INV_SCALE;
                sp[3] = a3 * H_INV_SCALE;
            }
            sidx = g_snext[sidx];
        }
    }
}

// ---- final layer for sampled rows ONLY, fused with the layer-2 sampled gather ----
__global__ void pull_sampled(const unsigned char* __restrict__ h,
                             const int* __restrict__ users, const int* __restrict__ pos,
                             const int* __restrict__ neg) {
    int wid  = (blockIdx.x * blockDim.x + threadIdx.x) >> 6;
    int lane = threadIdx.x & 63;
    if (wid >= 3 * BATCH) return;
    int which = wid / BATCH;
    int i     = wid - which * BATCH;
    const int* idx = (which == 0) ? users : ((which == 1) ? pos : neg);
    int node = idx[i];
    int g  = lane >> 4;
    int li = lane & 15;
    int beg = g_row_ptr[node], end = g_row_ptr[node + 1];
    float dinv_d = g_dinv[node];
    float a0 = 0.f, a1 = 0.f, a2 = 0.f, a3 = 0.f;
    for (int base = beg; base < end; base += 64) {
        int k = base + lane;
        int s = 0; float w = 0.0f;
        if (k < end) { s = g_csr[k]; w = g_dinv[s] * dinv_d; }
        int cnt = min(64, end - base);
        for (int j = 0; j < cnt; j += 8) {
            int   sA = __shfl(s, j + g);
            float wA = __shfl(w, j + g);
            int   sB = __shfl(s, j + 4 + g);
            float wB = __shfl(w, j + 4 + g);
            unsigned int dA = *(const unsigned int*)(h + (size_t)sA * DIM + li * 4);
            unsigned int dB = *(const unsigned int*)(h + (size_t)sB * DIM + li * 4);
            a0 = fmaf(wA, fp8_to_f32(dA),       a0);
            a1 = fmaf(wA, fp8_to_f32(dA >> 8),  a1);
            a2 = fmaf(wA, fp8_to_f32(dA >> 16), a2);
            a3 = fmaf(wA, fp8_to_f32(dA >> 24), a3);
            a0 = fmaf(wB, fp8_to_f32(dB),       a0);
            a1 = fmaf(wB, fp8_to_f32(dB >> 8),  a1);
            a2 = fmaf(wB, fp8_to_f32(dB >> 16), a2);
            a3 = fmaf(wB, fp8_to_f32(dB >> 24), a3);
        }
    }
    #pragma unroll
    for (int off = 16; off < 64; off <<= 1) {
        a0 += __shfl_xor(a0, off);
        a1 += __shfl_xor(a1, off);
        a2 += __shfl_xor(a2, off);
        a3 += __shfl_xor(a3, off);
    }
    if (lane < 16) {
        unsigned int dn = *(const unsigned int*)(h + (size_t)node * DIM + li * 4);
        float* sp = &g_sums[(size_t)wid * DIM + li * 4];
        sp[0] += (a0 + fp8_to_f32(dn))       * H_INV_SCALE;
        sp[1] += (a1 + fp8_to_f32(dn >> 8))  * H_INV_SCALE;
        sp[2] += (a2 + fp8_to_f32(dn >> 16)) * H_INV_SCALE;
        sp[3] += (a3 + fp8_to_f32(dn >> 24)) * H_INV_SCALE;
    }
}

// ---- per-sample scores + reg; layer-0 (emb) folded in here via u0/p0/n0 ----
__global__ void score_reduce(const float* __restrict__ emb,
                             const int* __restrict__ users, const int* __restrict__ pos,
                             const int* __restrict__ neg) {
    int wid  = (blockIdx.x * blockDim.x + threadIdx.x) >> 6;
    int lane = threadIdx.x & 63;
    if (wid >= BATCH) return;
    float u0 = emb[(size_t)users[wid] * DIM + lane];
    float p0 = emb[(size_t)pos[wid]   * DIM + lane];
    float n0 = emb[(size_t)neg[wid]   * DIM + lane];
    float u = 0.25f * (g_sums[(size_t)wid * DIM + lane] + u0);
    float p = 0.25f * (g_sums[(size_t)(BATCH + wid) * DIM + lane] + p0);
    float n = 0.25f * (g_sums[(size_t)(2 * BATCH + wid) * DIM + lane] + n0);
    float ps = u * p;
    float ns = u * n;
    float rg = u0 * u0 + p0 * p0 + n0 * n0;
    #pragma unroll
    for (int off = 32; off > 0; off >>= 1) {
        ps += __shfl_down(ps, off);
        ns += __shfl_down(ns, off);
        rg += __shfl_down(rg, off);
    }
    if (lane == 0) {
        float x  = ns - ps;
        float sp = fmaxf(x, 0.0f) + log1pf(expf(-fabsf(x)));  // stable softplus
        g_part_sp[wid] = sp;
        g_part_rg[wid] = rg;
    }
}

// ---- single-block final reduction over the 4096 per-wave partials ----
__global__ void final_reduce(float* __restrict__ out) {
    __shared__ float s_sp[256], s_rg[256];
    int t = threadIdx.x;
    float sp = 0.0f, rg = 0.0f;
    for (int i = t; i < BATCH; i += 256) { sp += g_part_sp[i]; rg += g_part_rg[i]; }
    s_sp[t] = sp; s_rg[t] = rg;
    __syncthreads();
    for (int off = 128; off > 0; off >>= 1) {
        if (t < off) { s_sp[t] += s_sp[t + off]; s_rg[t] += s_rg[t + off]; }
        __syncthreads();
    }
    if (t == 0) {
        float loss_emb = s_sp[0] / (float)BATCH;
        float reg      = 0.5f * s_rg[0] / (float)BATCH * REG_WEIGHT;
        out[0] = loss_emb + reg;
        out[1] = loss_emb;
        out[2] = reg;
    }
}

extern "C" void kernel_launch(void* const* d_in, const int* in_sizes, int n_in,
                              void* d_out, int out_size, void* d_ws, size_t ws_size,
                              hipStream_t stream) {
    const float* emb   = (const float*)d_in[0];
    const int*   src   = (const int*)d_in[1];
    const int*   dst   = (const int*)d_in[2];
    const int*   users = (const int*)d_in[3];
    const int*   pos   = (const int*)d_in[4];
    const int*   neg   = (const int*)d_in[5];
    const int E = in_sizes[1];
    float* out = (float*)d_out;

    unsigned char* hf_a;  hipGetSymbolAddress((void**)&hf_a, HIP_SYMBOL(g_hf8));
    unsigned char* hf_b = hf_a + (size_t)N_NODES * DIM;

    prelude<<<1024, 256, 0, stream>>>(emb);

    const int STAGE_BLOCKS = (E + 1024 * EDGES_PER_THREAD - 1) / (1024 * EDGES_PER_THREAD);
    stage_buckets<<<STAGE_BLOCKS, 1024, 0, stream>>>(src, dst, E, users, pos, neg);
    finalize_place<<<NBUCKET, 512, 0, stream>>>();

    // layer 1: full pull + fused sampled gather (assigns g_sums)
    pull_layer_fp8<<<(N_NODES * 64 + 255) / 256, 256, 0, stream>>>(hf_a, hf_b, 1);

    // layer 2: full pull (input to layer 3's sampled pull)
    pull_layer_fp8<<<(N_NODES * 64 + 255) / 256, 256, 0, stream>>>(hf_b, hf_a, 0);

    // layer 3 sampled pull + fused layer-2 sampled gather
    pull_sampled<<<(3 * BATCH * 64 + 255) / 256, 256, 0, stream>>>(hf_a, users, pos, neg);

    score_reduce<<<(BATCH * 64 + 255) / 256, 256, 0, stream>>>(emb, users, pos, neg);
    final_reduce<<<1, 256, 0, stream>>>(out);
}

// Round 15
// 197.566 us; speedup vs baseline: 2.7010x; 1.0611x over previous
//
#include <hip/hip_runtime.h>
#include <hip/hip_fp8.h>
#include <math.h>

#define N_NODES 100000
#define DIM 64
#define NUM_LAYER 3
#define BATCH 4096
#define REG_WEIGHT 1e-4f
#define NBUCKET 391                            // dst >> 8 buckets (256 nodes each)
#define STAGE_CAP 4096                         // fixed staging capacity per bucket (14 sigma)
#define CURPAD 16                              // ints: 64B pad per bucket cursor
#define H_SCALE 64.0f
#define H_INV_SCALE (1.0f / 64.0f)

typedef float floatx2 __attribute__((ext_vector_type(2)));

// Scratch as device globals (pattern passed R2..R14).
__device__ unsigned char g_hf8[2][(size_t)N_NODES * DIM]; // fp8 ping-pong h (scaled)
__device__ float g_sums[(size_t)3 * BATCH * DIM];  // sampled-row accumulators (f32)
__device__ int   g_row_ptr[N_NODES + 1];           // CSR row offsets (by dst)
__device__ float g_dinv[N_NODES];                  // deg^-0.5 (400 KB, L2-resident)
__device__ int   g_bcur[NBUCKET * CURPAD];         // padded bucket staging cursors
__device__ unsigned int g_stage[NBUCKET * STAGE_CAP]; // packed (src<<8)|(dst&255), 4B/edge
__device__ int   g_csr[1280000];                   // final CSR: src only, 4B/edge
__device__ int   g_shead[N_NODES];                 // node -> first sample idx (or -1)
__device__ int   g_snext[3 * BATCH];               // sample chain links
__device__ float g_part_sp[BATCH];                 // per-wave softplus partials
__device__ float g_part_rg[BATCH];                 // per-wave reg partials

// HW packed fp8 (OCP e4m3 on gfx950) converts: 2 values per instruction.
__device__ inline void fma4_fp8(unsigned int d, float w,
                                float& a0, float& a1, float& a2, float& a3) {
    floatx2 lo = __builtin_amdgcn_cvt_pk_f32_fp8((int)d, false);  // bytes 0,1
    floatx2 hi = __builtin_amdgcn_cvt_pk_f32_fp8((int)d, true);   // bytes 2,3
    a0 = fmaf(w, lo.x, a0); a1 = fmaf(w, lo.y, a1);
    a2 = fmaf(w, hi.x, a2); a3 = fmaf(w, hi.y, a3);
}
__device__ inline unsigned int pack4_fp8(float a0, float a1, float a2, float a3) {
    int w = __builtin_amdgcn_cvt_pk_fp8_f32(a0, a1, 0, false);
    w     = __builtin_amdgcn_cvt_pk_fp8_f32(a2, a3, w, true);
    return (unsigned int)w;
}

// ---- fused prelude: bcur init + shead init + emb->fp8 (HW cvt, dword stores) ----
__global__ void prelude(const float* __restrict__ emb) {
    int i = blockIdx.x * blockDim.x + threadIdx.x;
    int stride = gridDim.x * blockDim.x;
    for (int k = i; k < NBUCKET; k += stride) g_bcur[k * CURPAD] = k * STAGE_CAP;
    for (int k = i; k < N_NODES; k += stride) g_shead[k] = -1;
    const int NW = N_NODES * DIM / 4;
    unsigned int* hw = (unsigned int*)g_hf8[0];
    for (int k = i; k < NW; k += stride) {
        const float* e = emb + (size_t)k * 4;
        hw[k] = pack4_fp8(e[0] * H_SCALE, e[1] * H_SCALE,
                          e[2] * H_SCALE, e[3] * H_SCALE);
    }
}

// ---- stage pass: LDS histogram -> padded global reservations -> sequential-run
//      4B stores. Also builds the sample chain map (needs prelude's shead=-1). ----
#define EDGES_PER_THREAD 8
__global__ void __launch_bounds__(1024) stage_buckets(const int* __restrict__ src,
                                                      const int* __restrict__ dst, int E,
                                                      const int* __restrict__ users,
                                                      const int* __restrict__ pos,
                                                      const int* __restrict__ neg) {
    __shared__ int h[NBUCKET];
    __shared__ int cur[NBUCKET];
    int tid = threadIdx.x;
    int gt = blockIdx.x * 1024 + tid;
    if (gt < 3 * BATCH) {                       // build sample chains (12288 items)
        int which = gt / BATCH, s = gt - which * BATCH;
        const int* idx = (which == 0) ? users : ((which == 1) ? pos : neg);
        g_snext[gt] = atomicExch(&g_shead[idx[s]], gt);
    }
    int base = blockIdx.x * (1024 * EDGES_PER_THREAD);
    for (int i = tid; i < NBUCKET; i += 1024) h[i] = 0;
    __syncthreads();
    int myd[EDGES_PER_THREAD], mys[EDGES_PER_THREAD];
    #pragma unroll
    for (int k = 0; k < EDGES_PER_THREAD; ++k) {
        int e = base + k * 1024 + tid;
        if (e < E) {
            myd[k] = dst[e]; mys[k] = src[e];
            atomicAdd(&h[myd[k] >> 8], 1);
        } else myd[k] = -1;
    }
    __syncthreads();
    for (int i = tid; i < NBUCKET; i += 1024) {
        int c = h[i];
        cur[i] = c ? atomicAdd(&g_bcur[i * CURPAD], c) : 0;  // reserve run in bucket region
    }
    __syncthreads();
    #pragma unroll
    for (int k = 0; k < EDGES_PER_THREAD; ++k) {
        if (myd[k] >= 0) {
            int p = atomicAdd(&cur[myd[k] >> 8], 1);          // LDS cursor -> slot
            g_stage[p] = (unsigned int)((mys[k] << 8) | (myd[k] & 255));
        }
    }
}

// ---- fused per-bucket: 391-scan for base + degree hist + scan -> row_ptr/dinv,
//      then scatter into the bucket's CSR window (src only, 4B). NO global atomics. ----
__global__ void __launch_bounds__(512) finalize_place() {
    __shared__ int cs[512];
    __shared__ int lh[256], sc[256], cur[256];
    int b = blockIdx.x, t = threadIdx.x;
    int c = (t < NBUCKET) ? (g_bcur[t * CURPAD] - t * STAGE_CAP) : 0;
    cs[t] = c;
    __syncthreads();
    for (int off = 1; off < 512; off <<= 1) {
        int x = (t >= off) ? cs[t - off] : 0;
        __syncthreads();
        cs[t] += x;
        __syncthreads();
    }
    int mybase = (b > 0) ? cs[b - 1] : 0;         // exclusive prefix at bucket b
    int cnt    = cs[b] - mybase;
    if (b == 0 && t == 0) g_row_ptr[N_NODES] = cs[NBUCKET - 1];
    int sbeg = b * STAGE_CAP;
    if (t < 256) lh[t] = 0;
    __syncthreads();
    for (int k = t; k < cnt; k += 512)
        atomicAdd(&lh[g_stage[sbeg + k] & 255], 1);
    __syncthreads();
    int v = 0;
    if (t < 256) { v = lh[t]; sc[t] = v; }
    __syncthreads();
    for (int off = 1; off < 256; off <<= 1) {
        int x = (t >= off && t < 256) ? sc[t - off] : 0;
        __syncthreads();
        if (t < 256) sc[t] += x;
        __syncthreads();
    }
    if (t < 256) {
        int start = mybase + sc[t] - v;
        cur[t] = start;
        int node = (b << 8) + t;
        if (node < N_NODES) {
            g_row_ptr[node] = start;                          // exclusive
            g_dinv[node]    = (v > 0) ? rsqrtf((float)v) : 0.0f;
        }
    }
    __syncthreads();
    for (int k = t; k < cnt; k += 512) {                      // staged chunk is L2-hot
        unsigned int e = g_stage[sbeg + k];
        int pos = atomicAdd(&cur[e & 255], 1);
        g_csr[pos] = (int)(e >> 8);                           // src only
    }
}

// ---- pull one layer, dword-group form; 16 edges/iter (4 loads in flight/lane);
//      HW packed fp8 decode; w on the fly from L2-resident dinv. ----
__global__ void pull_layer_fp8(const unsigned char* __restrict__ h,
                               unsigned char* __restrict__ hn, int do_gather) {
    int wid  = (blockIdx.x * blockDim.x + threadIdx.x) >> 6;
    int lane = threadIdx.x & 63;
    if (wid >= N_NODES) return;
    int g  = lane >> 4;      // group 0..3 (edge slot)
    int li = lane & 15;      // dword index in row
    int beg = g_row_ptr[wid], end = g_row_ptr[wid + 1];
    float dinv_d = g_dinv[wid];
    float a0 = 0.f, a1 = 0.f, a2 = 0.f, a3 = 0.f;
    for (int base = beg; base < end; base += 64) {
        int k = base + lane;
        int s = 0; float w = 0.0f;
        if (k < end) { s = g_csr[k]; w = g_dinv[s] * dinv_d; }
        int cnt = min(64, end - base);
        for (int j = 0; j < cnt; j += 16) {       // max shfl idx = 48+12+3 = 63
            int   sA = __shfl(s, j + g),      sB = __shfl(s, j + 4 + g);
            int   sC = __shfl(s, j + 8 + g),  sD = __shfl(s, j + 12 + g);
            float wA = __shfl(w, j + g),      wB = __shfl(w, j + 4 + g);
            float wC = __shfl(w, j + 8 + g),  wD = __shfl(w, j + 12 + g);
            unsigned int dA = *(const unsigned int*)(h + (size_t)sA * DIM + li * 4);
            unsigned int dB = *(const unsigned int*)(h + (size_t)sB * DIM + li * 4);
            unsigned int dC = *(const unsigned int*)(h + (size_t)sC * DIM + li * 4);
            unsigned int dD = *(const unsigned int*)(h + (size_t)sD * DIM + li * 4);
            fma4_fp8(dA, wA, a0, a1, a2, a3);
            fma4_fp8(dB, wB, a0, a1, a2, a3);
            fma4_fp8(dC, wC, a0, a1, a2, a3);
            fma4_fp8(dD, wD, a0, a1, a2, a3);
        }
    }
    #pragma unroll
    for (int off = 16; off < 64; off <<= 1) {
        a0 += __shfl_xor(a0, off);
        a1 += __shfl_xor(a1, off);
        a2 += __shfl_xor(a2, off);
        a3 += __shfl_xor(a3, off);
    }
    if (lane < 16)
        *(unsigned int*)(hn + (size_t)wid * DIM + li * 4) = pack4_fp8(a0, a1, a2, a3);
    if (do_gather) {
        int sidx = g_shead[wid];                 // wave-uniform chain walk
        while (sidx >= 0) {
            if (lane < 16) {
                float* sp = &g_sums[(size_t)sidx * DIM + li * 4];
                sp[0] = a0 * H_INV_SCALE;        // ASSIGN: first writer of g_sums
                sp[1] = a1 * H_INV_SCALE;
                sp[2] = a2 * H_INV_SCALE;
                sp[3] = a3 * H_INV_SCALE;
            }
            sidx = g_snext[sidx];
        }
    }
}

// ---- final layer for sampled rows ONLY, fused with the layer-2 sampled gather ----
__global__ void pull_sampled(const unsigned char* __restrict__ h,
                             const int* __restrict__ users, const int* __restrict__ pos,
                             const int* __restrict__ neg) {
    int wid  = (blockIdx.x * blockDim.x + threadIdx.x) >> 6;
    int lane = threadIdx.x & 63;
    if (wid >= 3 * BATCH) return;
    int which = wid / BATCH;
    int i     = wid - which * BATCH;
    const int* idx = (which == 0) ? users : ((which == 1) ? pos : neg);
    int node = idx[i];
    int g  = lane >> 4;
    int li = lane & 15;
    int beg = g_row_ptr[node], end = g_row_ptr[node + 1];
    float dinv_d = g_dinv[node];
    float a0 = 0.f, a1 = 0.f, a2 = 0.f, a3 = 0.f;
    for (int base = beg; base < end; base += 64) {
        int k = base + lane;
        int s = 0; float w = 0.0f;
        if (k < end) { s = g_csr[k]; w = g_dinv[s] * dinv_d; }
        int cnt = min(64, end - base);
        for (int j = 0; j < cnt; j += 16) {
            int   sA = __shfl(s, j + g),      sB = __shfl(s, j + 4 + g);
            int   sC = __shfl(s, j + 8 + g),  sD = __shfl(s, j + 12 + g);
            float wA = __shfl(w, j + g),      wB = __shfl(w, j + 4 + g);
            float wC = __shfl(w, j + 8 + g),  wD = __shfl(w, j + 12 + g);
            unsigned int dA = *(const unsigned int*)(h + (size_t)sA * DIM + li * 4);
            unsigned int dB = *(const unsigned int*)(h + (size_t)sB * DIM + li * 4);
            unsigned int dC = *(const unsigned int*)(h + (size_t)sC * DIM + li * 4);
            unsigned int dD = *(const unsigned int*)(h + (size_t)sD * DIM + li * 4);
            fma4_fp8(dA, wA, a0, a1, a2, a3);
            fma4_fp8(dB, wB, a0, a1, a2, a3);
            fma4_fp8(dC, wC, a0, a1, a2, a3);
            fma4_fp8(dD, wD, a0, a1, a2, a3);
        }
    }
    #pragma unroll
    for (int off = 16; off < 64; off <<= 1) {
        a0 += __shfl_xor(a0, off);
        a1 += __shfl_xor(a1, off);
        a2 += __shfl_xor(a2, off);
        a3 += __shfl_xor(a3, off);
    }
    if (lane < 16) {
        unsigned int dn = *(const unsigned int*)(h + (size_t)node * DIM + li * 4);
        floatx2 lo = __builtin_amdgcn_cvt_pk_f32_fp8((int)dn, false);
        floatx2 hi = __builtin_amdgcn_cvt_pk_f32_fp8((int)dn, true);
        float* sp = &g_sums[(size_t)wid * DIM + li * 4];
        sp[0] += (a0 + lo.x) * H_INV_SCALE;
        sp[1] += (a1 + lo.y) * H_INV_SCALE;
        sp[2] += (a2 + hi.x) * H_INV_SCALE;
        sp[3] += (a3 + hi.y) * H_INV_SCALE;
    }
}

// ---- per-sample scores + reg; layer-0 (emb) folded in here via u0/p0/n0 ----
__global__ void score_reduce(const float* __restrict__ emb,
                             const int* __restrict__ users, const int* __restrict__ pos,
                             const int* __restrict__ neg) {
    int wid  = (blockIdx.x * blockDim.x + threadIdx.x) >> 6;
    int lane = threadIdx.x & 63;
    if (wid >= BATCH) return;
    float u0 = emb[(size_t)users[wid] * DIM + lane];
    float p0 = emb[(size_t)pos[wid]   * DIM + lane];
    float n0 = emb[(size_t)neg[wid]   * DIM + lane];
    float u = 0.25f * (g_sums[(size_t)wid * DIM + lane] + u0);
    float p = 0.25f * (g_sums[(size_t)(BATCH + wid) * DIM + lane] + p0);
    float n = 0.25f * (g_sums[(size_t)(2 * BATCH + wid) * DIM + lane] + n0);
    float ps = u * p;
    float ns = u * n;
    float rg = u0 * u0 + p0 * p0 + n0 * n0;
    #pragma unroll
    for (int off = 32; off > 0; off >>= 1) {
        ps += __shfl_down(ps, off);
        ns += __shfl_down(ns, off);
        rg += __shfl_down(rg, off);
    }
    if (lane == 0) {
        float x  = ns - ps;
        float sp = fmaxf(x, 0.0f) + log1pf(expf(-fabsf(x)));  // stable softplus
        g_part_sp[wid] = sp;
        g_part_rg[wid] = rg;
    }
}

// ---- single-block final reduction over the 4096 per-wave partials ----
__global__ void final_reduce(float* __restrict__ out) {
    __shared__ float s_sp[256], s_rg[256];
    int t = threadIdx.x;
    float sp = 0.0f, rg = 0.0f;
    for (int i = t; i < BATCH; i += 256) { sp += g_part_sp[i]; rg += g_part_rg[i]; }
    s_sp[t] = sp; s_rg[t] = rg;
    __syncthreads();
    for (int off = 128; off > 0; off >>= 1) {
        if (t < off) { s_sp[t] += s_sp[t + off]; s_rg[t] += s_rg[t + off]; }
        __syncthreads();
    }
    if (t == 0) {
        float loss_emb = s_sp[0] / (float)BATCH;
        float reg      = 0.5f * s_rg[0] / (float)BATCH * REG_WEIGHT;
        out[0] = loss_emb + reg;
        out[1] = loss_emb;
        out[2] = reg;
    }
}

extern "C" void kernel_launch(void* const* d_in, const int* in_sizes, int n_in,
                              void* d_out, int out_size, void* d_ws, size_t ws_size,
                              hipStream_t stream) {
    const float* emb   = (const float*)d_in[0];
    const int*   src   = (const int*)d_in[1];
    const int*   dst   = (const int*)d_in[2];
    const int*   users = (const int*)d_in[3];
    const int*   pos   = (const int*)d_in[4];
    const int*   neg   = (const int*)d_in[5];
    const int E = in_sizes[1];
    float* out = (float*)d_out;

    unsigned char* hf_a;  hipGetSymbolAddress((void**)&hf_a, HIP_SYMBOL(g_hf8));
    unsigned char* hf_b = hf_a + (size_t)N_NODES * DIM;

    prelude<<<1024, 256, 0, stream>>>(emb);

    const int STAGE_BLOCKS = (E + 1024 * EDGES_PER_THREAD - 1) / (1024 * EDGES_PER_THREAD);
    stage_buckets<<<STAGE_BLOCKS, 1024, 0, stream>>>(src, dst, E, users, pos, neg);
    finalize_place<<<NBUCKET, 512, 0, stream>>>();

    // layer 1: full pull + fused sampled gather (assigns g_sums)
    pull_layer_fp8<<<(N_NODES * 64 + 255) / 256, 256, 0, stream>>>(hf_a, hf_b, 1);

    // layer 2: full pull (input to layer 3's sampled pull)
    pull_layer_fp8<<<(N_NODES * 64 + 255) / 256, 256, 0, stream>>>(hf_b, hf_a, 0);

    // layer 3 sampled pull + fused layer-2 sampled gather
    pull_sampled<<<(3 * BATCH * 64 + 255) / 256, 256, 0, stream>>>(hf_a, users, pos, neg);

    score_reduce<<<(BATCH * 64 + 255) / 256, 256, 0, stream>>>(emb, users, pos, neg);
    final_reduce<<<1, 256, 0, stream>>>(out);
}

// Round 16
// 192.302 us; speedup vs baseline: 2.7749x; 1.0274x over previous
//
#include <hip/hip_runtime.h>
#include <hip/hip_fp8.h>
#include <math.h>

#define N_NODES 100000
#define DIM 64
#define NUM_LAYER 3
#define BATCH 4096
#define REG_WEIGHT 1e-4f
#define NBUCKET 391                            // dst >> 8 buckets (256 nodes each)
#define STAGE_CAP 4096                         // fixed staging capacity per bucket (14 sigma)
#define CURPAD 16                              // ints: 64B pad per bucket cursor
#define H_SCALE 64.0f
#define H_INV_SCALE (1.0f / 64.0f)

typedef float floatx2 __attribute__((ext_vector_type(2)));

// Scratch as device globals (pattern passed R2..R15).
__device__ unsigned char g_hf8[2][(size_t)N_NODES * DIM]; // fp8 ping-pong h (scaled)
__device__ float g_sums[(size_t)3 * BATCH * DIM];  // sampled-row accumulators (f32)
__device__ int   g_row_ptr[N_NODES + 1];           // CSR row offsets (by dst)
__device__ float g_dinv[N_NODES];                  // deg^-0.5 (400 KB, L2-resident)
__device__ int   g_bcur[NBUCKET * CURPAD];         // padded bucket staging cursors
__device__ unsigned int g_stage[NBUCKET * STAGE_CAP]; // packed (src<<8)|(dst&255), 4B/edge
__device__ int   g_csr[1280000];                   // final CSR: src only, 4B/edge
__device__ int   g_shead[N_NODES];                 // node -> first sample idx (or -1)
__device__ int   g_snext[3 * BATCH];               // sample chain links
__device__ float g_part_sp[BATCH];                 // per-wave softplus partials
__device__ float g_part_rg[BATCH];                 // per-wave reg partials

// HW packed fp8 (OCP e4m3 on gfx950) converts: 2 values per instruction.
__device__ inline void fma4_fp8(unsigned int d, float w,
                                float& a0, float& a1, float& a2, float& a3) {
    floatx2 lo = __builtin_amdgcn_cvt_pk_f32_fp8((int)d, false);  // bytes 0,1
    floatx2 hi = __builtin_amdgcn_cvt_pk_f32_fp8((int)d, true);   // bytes 2,3
    a0 = fmaf(w, lo.x, a0); a1 = fmaf(w, lo.y, a1);
    a2 = fmaf(w, hi.x, a2); a3 = fmaf(w, hi.y, a3);
}
__device__ inline unsigned int pack4_fp8(float a0, float a1, float a2, float a3) {
    int w = __builtin_amdgcn_cvt_pk_fp8_f32(a0, a1, 0, false);
    w     = __builtin_amdgcn_cvt_pk_fp8_f32(a2, a3, w, true);
    return (unsigned int)w;
}

// ---- fused prelude: bcur init + shead init + emb->fp8 (HW cvt, dword stores) ----
__global__ void prelude(const float* __restrict__ emb) {
    int i = blockIdx.x * blockDim.x + threadIdx.x;
    int stride = gridDim.x * blockDim.x;
    for (int k = i; k < NBUCKET; k += stride) g_bcur[k * CURPAD] = k * STAGE_CAP;
    for (int k = i; k < N_NODES; k += stride) g_shead[k] = -1;
    const int NW = N_NODES * DIM / 4;
    unsigned int* hw = (unsigned int*)g_hf8[0];
    for (int k = i; k < NW; k += stride) {
        const float* e = emb + (size_t)k * 4;
        hw[k] = pack4_fp8(e[0] * H_SCALE, e[1] * H_SCALE,
                          e[2] * H_SCALE, e[3] * H_SCALE);
    }
}

// ---- stage pass: LDS histogram -> padded global reservations -> sequential-run
//      4B stores. Also builds the sample chain map (needs prelude's shead=-1). ----
#define EDGES_PER_THREAD 8
__global__ void __launch_bounds__(1024) stage_buckets(const int* __restrict__ src,
                                                      const int* __restrict__ dst, int E,
                                                      const int* __restrict__ users,
                                                      const int* __restrict__ pos,
                                                      const int* __restrict__ neg) {
    __shared__ int h[NBUCKET];
    __shared__ int cur[NBUCKET];
    int tid = threadIdx.x;
    int gt = blockIdx.x * 1024 + tid;
    if (gt < 3 * BATCH) {                       // build sample chains (12288 items)
        int which = gt / BATCH, s = gt - which * BATCH;
        const int* idx = (which == 0) ? users : ((which == 1) ? pos : neg);
        g_snext[gt] = atomicExch(&g_shead[idx[s]], gt);
    }
    int base = blockIdx.x * (1024 * EDGES_PER_THREAD);
    for (int i = tid; i < NBUCKET; i += 1024) h[i] = 0;
    __syncthreads();
    int myd[EDGES_PER_THREAD], mys[EDGES_PER_THREAD];
    #pragma unroll
    for (int k = 0; k < EDGES_PER_THREAD; ++k) {
        int e = base + k * 1024 + tid;
        if (e < E) {
            myd[k] = dst[e]; mys[k] = src[e];
            atomicAdd(&h[myd[k] >> 8], 1);
        } else myd[k] = -1;
    }
    __syncthreads();
    for (int i = tid; i < NBUCKET; i += 1024) {
        int c = h[i];
        cur[i] = c ? atomicAdd(&g_bcur[i * CURPAD], c) : 0;  // reserve run in bucket region
    }
    __syncthreads();
    #pragma unroll
    for (int k = 0; k < EDGES_PER_THREAD; ++k) {
        if (myd[k] >= 0) {
            int p = atomicAdd(&cur[myd[k] >> 8], 1);          // LDS cursor -> slot
            g_stage[p] = (unsigned int)((mys[k] << 8) | (myd[k] & 255));
        }
    }
}

// ---- fused per-bucket: 391-scan for base + degree hist + scan -> row_ptr/dinv,
//      then scatter into the bucket's CSR window (src only, 4B). NO global atomics. ----
__global__ void __launch_bounds__(512) finalize_place() {
    __shared__ int cs[512];
    __shared__ int lh[256], sc[256], cur[256];
    int b = blockIdx.x, t = threadIdx.x;
    int c = (t < NBUCKET) ? (g_bcur[t * CURPAD] - t * STAGE_CAP) : 0;
    cs[t] = c;
    __syncthreads();
    for (int off = 1; off < 512; off <<= 1) {
        int x = (t >= off) ? cs[t - off] : 0;
        __syncthreads();
        cs[t] += x;
        __syncthreads();
    }
    int mybase = (b > 0) ? cs[b - 1] : 0;         // exclusive prefix at bucket b
    int cnt    = cs[b] - mybase;
    if (b == 0 && t == 0) g_row_ptr[N_NODES] = cs[NBUCKET - 1];
    int sbeg = b * STAGE_CAP;
    if (t < 256) lh[t] = 0;
    __syncthreads();
    for (int k = t; k < cnt; k += 512)
        atomicAdd(&lh[g_stage[sbeg + k] & 255], 1);
    __syncthreads();
    int v = 0;
    if (t < 256) { v = lh[t]; sc[t] = v; }
    __syncthreads();
    for (int off = 1; off < 256; off <<= 1) {
        int x = (t >= off && t < 256) ? sc[t - off] : 0;
        __syncthreads();
        if (t < 256) sc[t] += x;
        __syncthreads();
    }
    if (t < 256) {
        int start = mybase + sc[t] - v;
        cur[t] = start;
        int node = (b << 8) + t;
        if (node < N_NODES) {
            g_row_ptr[node] = start;                          // exclusive
            g_dinv[node]    = (v > 0) ? rsqrtf((float)v) : 0.0f;
        }
    }
    __syncthreads();
    for (int k = t; k < cnt; k += 512) {                      // staged chunk is L2-hot
        unsigned int e = g_stage[sbeg + k];
        int pos = atomicAdd(&cur[e & 255], 1);
        g_csr[pos] = (int)(e >> 8);                           // src only
    }
}

// ---- pull one layer, TWO nodes per wave: interleaved gathers double per-lane MLP
//      (8 loads in flight). HW fp8 decode; w on the fly from L2-resident dinv. ----
__global__ void pull_layer_fp8(const unsigned char* __restrict__ h,
                               unsigned char* __restrict__ hn, int do_gather) {
    int wid  = (blockIdx.x * blockDim.x + threadIdx.x) >> 6;
    int lane = threadIdx.x & 63;
    int nA = wid * 2, nB = nA + 1;
    if (nA >= N_NODES) return;
    bool hasB = (nB < N_NODES);
    int g  = lane >> 4;      // group 0..3 (edge slot)
    int li = lane & 15;      // dword index in row
    int begA = g_row_ptr[nA], endA = g_row_ptr[nA + 1];
    int begB = hasB ? g_row_ptr[nB] : 0, endB = hasB ? g_row_ptr[nB + 1] : 0;
    float dinvA = g_dinv[nA];
    float dinvB = hasB ? g_dinv[nB] : 0.0f;
    int lenA = endA - begA, lenB = endB - begB;
    int maxLen = max(lenA, lenB);
    float aA0 = 0.f, aA1 = 0.f, aA2 = 0.f, aA3 = 0.f;
    float aB0 = 0.f, aB1 = 0.f, aB2 = 0.f, aB3 = 0.f;
    for (int off = 0; off < maxLen; off += 64) {
        int kA = off + lane;
        int sA = 0; float wA = 0.0f;
        if (kA < lenA) { sA = g_csr[begA + kA]; wA = g_dinv[sA] * dinvA; }
        int sB = 0; float wB = 0.0f;
        if (kA < lenB) { sB = g_csr[begB + kA]; wB = g_dinv[sB] * dinvB; }
        int cnt = min(64, maxLen - off);
        for (int j = 0; j < cnt; j += 16) {       // max shfl idx = 48+12+3 = 63
            int   sA1 = __shfl(sA, j + g),      sA2 = __shfl(sA, j + 4 + g);
            int   sA3 = __shfl(sA, j + 8 + g),  sA4 = __shfl(sA, j + 12 + g);
            int   sB1 = __shfl(sB, j + g),      sB2 = __shfl(sB, j + 4 + g);
            int   sB3 = __shfl(sB, j + 8 + g),  sB4 = __shfl(sB, j + 12 + g);
            float wA1 = __shfl(wA, j + g),      wA2 = __shfl(wA, j + 4 + g);
            float wA3 = __shfl(wA, j + 8 + g),  wA4 = __shfl(wA, j + 12 + g);
            float wB1 = __shfl(wB, j + g),      wB2 = __shfl(wB, j + 4 + g);
            float wB3 = __shfl(wB, j + 8 + g),  wB4 = __shfl(wB, j + 12 + g);
            // 8 independent gathers in flight before first consume
            unsigned int dA1 = *(const unsigned int*)(h + (size_t)sA1 * DIM + li * 4);
            unsigned int dA2 = *(const unsigned int*)(h + (size_t)sA2 * DIM + li * 4);
            unsigned int dA3 = *(const unsigned int*)(h + (size_t)sA3 * DIM + li * 4);
            unsigned int dA4 = *(const unsigned int*)(h + (size_t)sA4 * DIM + li * 4);
            unsigned int dB1 = *(const unsigned int*)(h + (size_t)sB1 * DIM + li * 4);
            unsigned int dB2 = *(const unsigned int*)(h + (size_t)sB2 * DIM + li * 4);
            unsigned int dB3 = *(const unsigned int*)(h + (size_t)sB3 * DIM + li * 4);
            unsigned int dB4 = *(const unsigned int*)(h + (size_t)sB4 * DIM + li * 4);
            fma4_fp8(dA1, wA1, aA0, aA1, aA2, aA3);
            fma4_fp8(dA2, wA2, aA0, aA1, aA2, aA3);
            fma4_fp8(dA3, wA3, aA0, aA1, aA2, aA3);
            fma4_fp8(dA4, wA4, aA0, aA1, aA2, aA3);
            fma4_fp8(dB1, wB1, aB0, aB1, aB2, aB3);
            fma4_fp8(dB2, wB2, aB0, aB1, aB2, aB3);
            fma4_fp8(dB3, wB3, aB0, aB1, aB2, aB3);
            fma4_fp8(dB4, wB4, aB0, aB1, aB2, aB3);
        }
    }
    #pragma unroll
    for (int off = 16; off < 64; off <<= 1) {
        aA0 += __shfl_xor(aA0, off); aA1 += __shfl_xor(aA1, off);
        aA2 += __shfl_xor(aA2, off); aA3 += __shfl_xor(aA3, off);
        aB0 += __shfl_xor(aB0, off); aB1 += __shfl_xor(aB1, off);
        aB2 += __shfl_xor(aB2, off); aB3 += __shfl_xor(aB3, off);
    }
    if (lane < 16) {
        *(unsigned int*)(hn + (size_t)nA * DIM + li * 4) = pack4_fp8(aA0, aA1, aA2, aA3);
        if (hasB)
            *(unsigned int*)(hn + (size_t)nB * DIM + li * 4) = pack4_fp8(aB0, aB1, aB2, aB3);
    }
    if (do_gather) {
        int sidx = g_shead[nA];                  // wave-uniform chain walks
        while (sidx >= 0) {
            if (lane < 16) {
                float* sp = &g_sums[(size_t)sidx * DIM + li * 4];
                sp[0] = aA0 * H_INV_SCALE; sp[1] = aA1 * H_INV_SCALE;
                sp[2] = aA2 * H_INV_SCALE; sp[3] = aA3 * H_INV_SCALE;
            }
            sidx = g_snext[sidx];
        }
        if (hasB) {
            sidx = g_shead[nB];
            while (sidx >= 0) {
                if (lane < 16) {
                    float* sp = &g_sums[(size_t)sidx * DIM + li * 4];
                    sp[0] = aB0 * H_INV_SCALE; sp[1] = aB1 * H_INV_SCALE;
                    sp[2] = aB2 * H_INV_SCALE; sp[3] = aB3 * H_INV_SCALE;
                }
                sidx = g_snext[sidx];
            }
        }
    }
}

// ---- final layer for sampled rows ONLY, fused with the layer-2 sampled gather ----
__global__ void pull_sampled(const unsigned char* __restrict__ h,
                             const int* __restrict__ users, const int* __restrict__ pos,
                             const int* __restrict__ neg) {
    int wid  = (blockIdx.x * blockDim.x + threadIdx.x) >> 6;
    int lane = threadIdx.x & 63;
    if (wid >= 3 * BATCH) return;
    int which = wid / BATCH;
    int i     = wid - which * BATCH;
    const int* idx = (which == 0) ? users : ((which == 1) ? pos : neg);
    int node = idx[i];
    int g  = lane >> 4;
    int li = lane & 15;
    int beg = g_row_ptr[node], end = g_row_ptr[node + 1];
    float dinv_d = g_dinv[node];
    float a0 = 0.f, a1 = 0.f, a2 = 0.f, a3 = 0.f;
    for (int base = beg; base < end; base += 64) {
        int k = base + lane;
        int s = 0; float w = 0.0f;
        if (k < end) { s = g_csr[k]; w = g_dinv[s] * dinv_d; }
        int cnt = min(64, end - base);
        for (int j = 0; j < cnt; j += 16) {
            int   sA = __shfl(s, j + g),      sB = __shfl(s, j + 4 + g);
            int   sC = __shfl(s, j + 8 + g),  sD = __shfl(s, j + 12 + g);
            float wA = __shfl(w, j + g),      wB = __shfl(w, j + 4 + g);
            float wC = __shfl(w, j + 8 + g),  wD = __shfl(w, j + 12 + g);
            unsigned int dA = *(const unsigned int*)(h + (size_t)sA * DIM + li * 4);
            unsigned int dB = *(const unsigned int*)(h + (size_t)sB * DIM + li * 4);
            unsigned int dC = *(const unsigned int*)(h + (size_t)sC * DIM + li * 4);
            unsigned int dD = *(const unsigned int*)(h + (size_t)sD * DIM + li * 4);
            fma4_fp8(dA, wA, a0, a1, a2, a3);
            fma4_fp8(dB, wB, a0, a1, a2, a3);
            fma4_fp8(dC, wC, a0, a1, a2, a3);
            fma4_fp8(dD, wD, a0, a1, a2, a3);
        }
    }
    #pragma unroll
    for (int off = 16; off < 64; off <<= 1) {
        a0 += __shfl_xor(a0, off);
        a1 += __shfl_xor(a1, off);
        a2 += __shfl_xor(a2, off);
        a3 += __shfl_xor(a3, off);
    }
    if (lane < 16) {
        unsigned int dn = *(const unsigned int*)(h + (size_t)node * DIM + li * 4);
        floatx2 lo = __builtin_amdgcn_cvt_pk_f32_fp8((int)dn, false);
        floatx2 hi = __builtin_amdgcn_cvt_pk_f32_fp8((int)dn, true);
        float* sp = &g_sums[(size_t)wid * DIM + li * 4];
        sp[0] += (a0 + lo.x) * H_INV_SCALE;
        sp[1] += (a1 + lo.y) * H_INV_SCALE;
        sp[2] += (a2 + hi.x) * H_INV_SCALE;
        sp[3] += (a3 + hi.y) * H_INV_SCALE;
    }
}

// ---- per-sample scores + reg; layer-0 (emb) folded in here via u0/p0/n0 ----
__global__ void score_reduce(const float* __restrict__ emb,
                             const int* __restrict__ users, const int* __restrict__ pos,
                             const int* __restrict__ neg) {
    int wid  = (blockIdx.x * blockDim.x + threadIdx.x) >> 6;
    int lane = threadIdx.x & 63;
    if (wid >= BATCH) return;
    float u0 = emb[(size_t)users[wid] * DIM + lane];
    float p0 = emb[(size_t)pos[wid]   * DIM + lane];
    float n0 = emb[(size_t)neg[wid]   * DIM + lane];
    float u = 0.25f * (g_sums[(size_t)wid * DIM + lane] + u0);
    float p = 0.25f * (g_sums[(size_t)(BATCH + wid) * DIM + lane] + p0);
    float n = 0.25f * (g_sums[(size_t)(2 * BATCH + wid) * DIM + lane] + n0);
    float ps = u * p;
    float ns = u * n;
    float rg = u0 * u0 + p0 * p0 + n0 * n0;
    #pragma unroll
    for (int off = 32; off > 0; off >>= 1) {
        ps += __shfl_down(ps, off);
        ns += __shfl_down(ns, off);
        rg += __shfl_down(rg, off);
    }
    if (lane == 0) {
        float x  = ns - ps;
        float sp = fmaxf(x, 0.0f) + log1pf(expf(-fabsf(x)));  // stable softplus
        g_part_sp[wid] = sp;
        g_part_rg[wid] = rg;
    }
}

// ---- single-block final reduction over the 4096 per-wave partials ----
__global__ void final_reduce(float* __restrict__ out) {
    __shared__ float s_sp[256], s_rg[256];
    int t = threadIdx.x;
    float sp = 0.0f, rg = 0.0f;
    for (int i = t; i < BATCH; i += 256) { sp += g_part_sp[i]; rg += g_part_rg[i]; }
    s_sp[t] = sp; s_rg[t] = rg;
    __syncthreads();
    for (int off = 128; off > 0; off >>= 1) {
        if (t < off) { s_sp[t] += s_sp[t + off]; s_rg[t] += s_rg[t + off]; }
        __syncthreads();
    }
    if (t == 0) {
        float loss_emb = s_sp[0] / (float)BATCH;
        float reg      = 0.5f * s_rg[0] / (float)BATCH * REG_WEIGHT;
        out[0] = loss_emb + reg;
        out[1] = loss_emb;
        out[2] = reg;
    }
}

extern "C" void kernel_launch(void* const* d_in, const int* in_sizes, int n_in,
                              void* d_out, int out_size, void* d_ws, size_t ws_size,
                              hipStream_t stream) {
    const float* emb   = (const float*)d_in[0];
    const int*   src   = (const int*)d_in[1];
    const int*   dst   = (const int*)d_in[2];
    const int*   users = (const int*)d_in[3];
    const int*   pos   = (const int*)d_in[4];
    const int*   neg   = (const int*)d_in[5];
    const int E = in_sizes[1];
    float* out = (float*)d_out;

    unsigned char* hf_a;  hipGetSymbolAddress((void**)&hf_a, HIP_SYMBOL(g_hf8));
    unsigned char* hf_b = hf_a + (size_t)N_NODES * DIM;

    prelude<<<1024, 256, 0, stream>>>(emb);

    const int STAGE_BLOCKS = (E + 1024 * EDGES_PER_THREAD - 1) / (1024 * EDGES_PER_THREAD);
    stage_buckets<<<STAGE_BLOCKS, 1024, 0, stream>>>(src, dst, E, users, pos, neg);
    finalize_place<<<NBUCKET, 512, 0, stream>>>();

    const int NPAIR = (N_NODES + 1) / 2;           // 2 nodes per wave
    const int PULL_BLOCKS = (NPAIR * 64 + 255) / 256;

    // layer 1: full pull + fused sampled gather (assigns g_sums)
    pull_layer_fp8<<<PULL_BLOCKS, 256, 0, stream>>>(hf_a, hf_b, 1);

    // layer 2: full pull (input to layer 3's sampled pull)
    pull_layer_fp8<<<PULL_BLOCKS, 256, 0, stream>>>(hf_b, hf_a, 0);

    // layer 3 sampled pull + fused layer-2 sampled gather
    pull_sampled<<<(3 * BATCH * 64 + 255) / 256, 256, 0, stream>>>(hf_a, users, pos, neg);

    score_reduce<<<(BATCH * 64 + 255) / 256, 256, 0, stream>>>(emb, users, pos, neg);
    final_reduce<<<1, 256, 0, stream>>>(out);
}